// Round 1
// baseline (167.121 us; speedup 1.0000x reference)
//
#include <hip/hip_runtime.h>

typedef __bf16 bf16;
typedef __bf16 bf16x8 __attribute__((ext_vector_type(8)));
typedef float f32x4 __attribute__((ext_vector_type(4)));

#define B_ 2
#define C_ 512
#define HW_ 2304
#define GROUPS_ 32
#define CPG_ 16
#define EPS_ 1e-5f

// ---------------------------------------------------------------- gn stats
__global__ __launch_bounds__(256) void gn_stats_k(const float* __restrict__ x,
                                                  float* __restrict__ mean,
                                                  float* __restrict__ rstd) {
  int bg = blockIdx.x;  // b*32+g  (16 contiguous channels per group)
  const float4* p = (const float4*)(x + (long)bg * CPG_ * HW_);
  const int n4 = CPG_ * HW_ / 4;  // 9216
  float s = 0.f, ss = 0.f;
  for (int i = threadIdx.x; i < n4; i += 256) {
    float4 v = p[i];
    s += v.x + v.y + v.z + v.w;
    ss += v.x * v.x + v.y * v.y + v.z * v.z + v.w * v.w;
  }
#pragma unroll
  for (int d = 1; d < 64; d <<= 1) { s += __shfl_xor(s, d); ss += __shfl_xor(ss, d); }
  __shared__ float rs[4], rss[4];
  int wave = threadIdx.x >> 6, lane = threadIdx.x & 63;
  if (lane == 0) { rs[wave] = s; rss[wave] = ss; }
  __syncthreads();
  if (threadIdx.x == 0) {
    float S = rs[0] + rs[1] + rs[2] + rs[3];
    float SS = rss[0] + rss[1] + rss[2] + rss[3];
    float mu = S / (float)(CPG_ * HW_);
    float var = SS / (float)(CPG_ * HW_) - mu * mu;
    mean[bg] = mu;
    rstd[bg] = rsqrtf(var + EPS_);
  }
}

// ------------------------------------------------- gn apply + transpose->bf16
// writes xnT[b][n][c]  (n-major), bf16
__global__ __launch_bounds__(256) void gn_apply_k(const float* __restrict__ x,
                                                  const float* __restrict__ gw,
                                                  const float* __restrict__ gb,
                                                  const float* __restrict__ mean,
                                                  const float* __restrict__ rstd,
                                                  bf16* __restrict__ xnT) {
  // grid: (HW_/64, C_/32, B_)
  int n0 = blockIdx.x * 64, c0 = blockIdx.y * 32, b = blockIdx.z;
  int nn = n0 + (threadIdx.x & 63);
  int cb = c0 + ((threadIdx.x >> 6) << 3);
  bf16x8 o;
#pragma unroll
  for (int j = 0; j < 8; ++j) {
    int c = cb + j;
    int gi = b * GROUPS_ + (c >> 4);
    float sc = rstd[gi] * gw[c];
    float sh = gb[c] - mean[gi] * sc;
    float v = x[((long)b * C_ + c) * HW_ + nn];
    o[j] = (bf16)(v * sc + sh);
  }
  *(bf16x8*)&xnT[((long)b * HW_ + nn) * C_ + cb] = o;
}

// ------------------------------------------------------- weight prep (bf16)
// qkv channel interleave: o = 3*(head*64+dd)+t  ->  gather rows.
// wqk rows: r<512 -> q row r (scaled by 0.125), r>=512 -> k row (r-512)
__global__ __launch_bounds__(256) void prep_w_k(const float* __restrict__ qkv_w,
                                                const float* __restrict__ qkv_b,
                                                const float* __restrict__ proj_w,
                                                bf16* __restrict__ wqk,
                                                bf16* __restrict__ wv,
                                                bf16* __restrict__ wp,
                                                float* __restrict__ bqk,
                                                float* __restrict__ bv) {
  int idx = blockIdx.x * 256 + threadIdx.x;  // exactly 1024*512 threads
  int r = idx >> 9, c = idx & 511;
  {
    int src = (r < 512) ? 3 * r : 3 * (r - 512) + 1;
    float sc = (r < 512) ? 0.125f : 1.0f;
    wqk[idx] = (bf16)(qkv_w[(long)src * 512 + c] * sc);
  }
  if (r < 512) {
    wv[idx] = (bf16)(qkv_w[(long)(3 * r + 2) * 512 + c]);
    wp[idx] = (bf16)(proj_w[idx]);
  }
  if (idx < 1024) {
    int src = (idx < 512) ? 3 * idx : 3 * (idx - 512) + 1;
    float sc = (idx < 512) ? 0.125f : 1.0f;
    bqk[idx] = qkv_b[src] * sc;
  }
  if (idx < 512) bv[idx] = qkv_b[3 * idx + 2];
}

// ------------------------------------------------------------ generic GEMM
// C[M][N] = A(MxK rowmajor) * B, where B is given transposed: BT(NxK rowmajor).
// 64x64 tile, 4 waves (2x2 of 32x32), K-step 32, mfma 16x16x32 bf16.
template <int BIAS_MODE /*0 none,1 per-row,2 per-col*/, bool RESID, typename OUT_T>
__global__ __launch_bounds__(256) void gemm_bt_k(const bf16* __restrict__ A,
                                                 const bf16* __restrict__ BT,
                                                 const float* __restrict__ bias,
                                                 const float* __restrict__ resid,
                                                 OUT_T* __restrict__ Cc,
                                                 int M, int N, int K,
                                                 long sA, long sBT, long sC) {
  int b = blockIdx.z;
  A += sA * b;
  BT += sBT * b;
  Cc += sC * b;
  const float* R = RESID ? (resid + sC * b) : nullptr;
  int m0 = blockIdx.y * 64, n0 = blockIdx.x * 64;
  int tid = threadIdx.x, lane = tid & 63, wave = tid >> 6;
  int wm = (wave >> 1) << 5, wn = (wave & 1) << 5;
  int fr = lane & 15, kg = (lane >> 4) << 3;
  __shared__ __align__(16) bf16 As[64][40];
  __shared__ __align__(16) bf16 Bs[64][40];
  int lr = tid >> 2, lk = (tid & 3) << 3;
  const bf16* ga = A + (long)(m0 + lr) * K + lk;
  const bf16* gbp = BT + (long)(n0 + lr) * K + lk;
  f32x4 acc[2][2] = {};
  for (int k0 = 0; k0 < K; k0 += 32) {
    __syncthreads();
    *(uint4*)&As[lr][lk] = *(const uint4*)(ga + k0);
    *(uint4*)&Bs[lr][lk] = *(const uint4*)(gbp + k0);
    __syncthreads();
    bf16x8 a0 = *(bf16x8*)&As[wm + fr][kg];
    bf16x8 a1 = *(bf16x8*)&As[wm + 16 + fr][kg];
    bf16x8 b0 = *(bf16x8*)&Bs[wn + fr][kg];
    bf16x8 b1 = *(bf16x8*)&Bs[wn + 16 + fr][kg];
    acc[0][0] = __builtin_amdgcn_mfma_f32_16x16x32_bf16(a0, b0, acc[0][0], 0, 0, 0);
    acc[0][1] = __builtin_amdgcn_mfma_f32_16x16x32_bf16(a0, b1, acc[0][1], 0, 0, 0);
    acc[1][0] = __builtin_amdgcn_mfma_f32_16x16x32_bf16(a1, b0, acc[1][0], 0, 0, 0);
    acc[1][1] = __builtin_amdgcn_mfma_f32_16x16x32_bf16(a1, b1, acc[1][1], 0, 0, 0);
  }
  int rbase = (lane >> 4) << 2;
#pragma unroll
  for (int mi = 0; mi < 2; ++mi)
#pragma unroll
    for (int nj = 0; nj < 2; ++nj)
#pragma unroll
      for (int reg = 0; reg < 4; ++reg) {
        int row = m0 + wm + (mi << 4) + rbase + reg;
        int col = n0 + wn + (nj << 4) + fr;
        float v = acc[mi][nj][reg];
        if (BIAS_MODE == 1) v += bias[row];
        if (BIAS_MODE == 2) v += bias[col];
        if (RESID) v += R[(long)row * N + col];
        Cc[(long)row * N + col] = (OUT_T)v;
      }
}

// ------------------------------------------------------------- attention
// yT[b][n][0:512)=q (prescaled), [512:1024)=k ; V[b][hd][n] ; out aT[b][n][c]
__global__ __launch_bounds__(256) void attn_k(const bf16* __restrict__ yT,
                                              const bf16* __restrict__ V,
                                              bf16* __restrict__ aT) {
  const int n = HW_;
  int bh = blockIdx.y, b = bh >> 3, h = bh & 7;
  int q0 = blockIdx.x * 64;
  int tid = threadIdx.x, lane = tid & 63, wave = tid >> 6;
  int fr = lane & 15, kg = (lane >> 4) << 3;
  const bf16* yTb = yT + (long)b * n * 1024;
  const bf16* Vb = V + ((long)b * C_ + h * 64) * n;  // rows = dd
  // each wave owns 16 q rows; q fragments live in registers for the whole loop
  int qrow = q0 + (wave << 4) + fr;
  const bf16* qp = yTb + (long)qrow * 1024 + h * 64;
  bf16x8 qf0 = *(const bf16x8*)(qp + kg);
  bf16x8 qf1 = *(const bf16x8*)(qp + 32 + kg);

  __shared__ __align__(16) bf16 Kt[64][72];      // [ki][dd]
  __shared__ __align__(16) bf16 Vt[64][72];      // [dd][ki]
  __shared__ __align__(16) bf16 Pt[4][16][72];   // per-wave P [qi][ki]

  float m_run[4], l_run[4];
  f32x4 oacc[4] = {};
#pragma unroll
  for (int r = 0; r < 4; ++r) { m_run[r] = -3e38f; l_run[r] = 0.f; }

  for (int k0 = 0; k0 < n; k0 += 64) {
#pragma unroll
    for (int it = 0; it < 2; ++it) {
      int cidx = tid + (it << 8);
      int rr = cidx >> 3, ch = (cidx & 7) << 3;
      *(uint4*)&Kt[rr][ch] = *(const uint4*)&yTb[(long)(k0 + rr) * 1024 + 512 + h * 64 + ch];
      *(uint4*)&Vt[rr][ch] = *(const uint4*)&Vb[(long)rr * n + k0 + ch];
    }
    __syncthreads();
    // S = q @ k^T  (16 x 64 per wave)
    f32x4 s[4] = {};
#pragma unroll
    for (int nj = 0; nj < 4; ++nj) {
      bf16x8 kf0 = *(bf16x8*)&Kt[(nj << 4) + fr][kg];
      bf16x8 kf1 = *(bf16x8*)&Kt[(nj << 4) + fr][32 + kg];
      s[nj] = __builtin_amdgcn_mfma_f32_16x16x32_bf16(qf0, kf0, s[nj], 0, 0, 0);
      s[nj] = __builtin_amdgcn_mfma_f32_16x16x32_bf16(qf1, kf1, s[nj], 0, 0, 0);
    }
    // online softmax; lane holds rows rbase..rbase+3, col fr of each nj
    float tmax[4];
#pragma unroll
    for (int r = 0; r < 4; ++r)
      tmax[r] = fmaxf(fmaxf(s[0][r], s[1][r]), fmaxf(s[2][r], s[3][r]));
#pragma unroll
    for (int d = 1; d < 16; d <<= 1)
#pragma unroll
      for (int r = 0; r < 4; ++r) tmax[r] = fmaxf(tmax[r], __shfl_xor(tmax[r], d));
    float corr[4], psum[4];
#pragma unroll
    for (int r = 0; r < 4; ++r) {
      float mn = fmaxf(m_run[r], tmax[r]);
      corr[r] = __expf(m_run[r] - mn);
      m_run[r] = mn;
      psum[r] = 0.f;
    }
    int rbase = (lane >> 4) << 2;
#pragma unroll
    for (int nj = 0; nj < 4; ++nj)
#pragma unroll
      for (int r = 0; r < 4; ++r) {
        float p = __expf(s[nj][r] - m_run[r]);
        psum[r] += p;
        Pt[wave][rbase + r][(nj << 4) + fr] = (bf16)p;
      }
#pragma unroll
    for (int d = 1; d < 16; d <<= 1)
#pragma unroll
      for (int r = 0; r < 4; ++r) psum[r] += __shfl_xor(psum[r], d);
#pragma unroll
    for (int r = 0; r < 4; ++r) l_run[r] = l_run[r] * corr[r] + psum[r];
#pragma unroll
    for (int dj = 0; dj < 4; ++dj)
#pragma unroll
      for (int r = 0; r < 4; ++r) oacc[dj][r] *= corr[r];
    __syncthreads();  // Pt visible (and Kt reads done)
    // O += P @ V   (16 x 64 per wave)
    bf16x8 pf0 = *(bf16x8*)&Pt[wave][fr][kg];
    bf16x8 pf1 = *(bf16x8*)&Pt[wave][fr][32 + kg];
#pragma unroll
    for (int dj = 0; dj < 4; ++dj) {
      bf16x8 vf0 = *(bf16x8*)&Vt[(dj << 4) + fr][kg];
      bf16x8 vf1 = *(bf16x8*)&Vt[(dj << 4) + fr][32 + kg];
      oacc[dj] = __builtin_amdgcn_mfma_f32_16x16x32_bf16(pf0, vf0, oacc[dj], 0, 0, 0);
      oacc[dj] = __builtin_amdgcn_mfma_f32_16x16x32_bf16(pf1, vf1, oacc[dj], 0, 0, 0);
    }
    __syncthreads();  // PV reads done before next stage
  }
  int rbase = (lane >> 4) << 2;
  float inv[4];
#pragma unroll
  for (int r = 0; r < 4; ++r) inv[r] = 1.f / l_run[r];
#pragma unroll
  for (int dj = 0; dj < 4; ++dj)
#pragma unroll
    for (int r = 0; r < 4; ++r) {
      int row = q0 + (wave << 4) + rbase + r;
      int col = h * 64 + (dj << 4) + fr;
      aT[((long)b * n + row) * C_ + col] = (bf16)(oacc[dj][r] * inv[r]);
    }
}

// ----------------------------------------------------------------- launch
extern "C" void kernel_launch(void* const* d_in, const int* in_sizes, int n_in,
                              void* d_out, int out_size, void* d_ws, size_t ws_size,
                              hipStream_t stream) {
  const float* x = (const float*)d_in[0];
  const float* gn_w = (const float*)d_in[1];
  const float* gn_b = (const float*)d_in[2];
  const float* qkv_w = (const float*)d_in[3];
  const float* qkv_b = (const float*)d_in[4];
  const float* proj_w = (const float*)d_in[5];
  const float* proj_b = (const float*)d_in[6];
  float* out = (float*)d_out;

  char* ws = (char*)d_ws;
  float* mean = (float*)ws; ws += 256;
  float* rstd = (float*)ws; ws += 256;
  float* bqk = (float*)ws;  ws += 4096;
  float* bv = (float*)ws;   ws += 2048;
  bf16* wqk = (bf16*)ws;    ws += 1024l * 512 * 2;
  bf16* wv = (bf16*)ws;     ws += 512l * 512 * 2;
  bf16* wp = (bf16*)ws;     ws += 512l * 512 * 2;
  bf16* xnT = (bf16*)ws;    ws += 2l * HW_ * 512 * 2;
  bf16* yT = (bf16*)ws;     ws += 2l * HW_ * 1024 * 2;
  bf16* v = (bf16*)ws;      ws += 2l * 512 * HW_ * 2;
  bf16* aT = (bf16*)ws;     ws += 2l * HW_ * 512 * 2;

  gn_stats_k<<<64, 256, 0, stream>>>(x, mean, rstd);
  prep_w_k<<<2048, 256, 0, stream>>>(qkv_w, qkv_b, proj_w, wqk, wv, wp, bqk, bv);
  gn_apply_k<<<dim3(36, 16, 2), 256, 0, stream>>>(x, gn_w, gn_b, mean, rstd, xnT);
  // yT[b][n][r] = xnT @ wqk^T + bqk   (M=2304, N=1024, K=512)
  gemm_bt_k<2, false, bf16><<<dim3(16, 36, 2), 256, 0, stream>>>(
      xnT, wqk, bqk, nullptr, yT, 2304, 1024, 512, (long)HW_ * 512, 0, (long)HW_ * 1024);
  // v[b][hd][n] = wv @ xn + bv        (M=512, N=2304, K=512)
  gemm_bt_k<1, false, bf16><<<dim3(36, 8, 2), 256, 0, stream>>>(
      wv, xnT, bv, nullptr, v, 512, 2304, 512, 0, (long)HW_ * 512, 512l * HW_);
  attn_k<<<dim3(36, 16), 256, 0, stream>>>(yT, v, aT);
  // out[b][o][n] = wp @ a + proj_b + x  (M=512, N=2304, K=512), fp32 out
  gemm_bt_k<1, true, float><<<dim3(36, 8, 2), 256, 0, stream>>>(
      wp, aT, proj_b, x, out, 512, 2304, 512, 0, (long)HW_ * 512, 512l * HW_);
}

// Round 2
// 133.893 us; speedup vs baseline: 1.2482x; 1.2482x over previous
//
#include <hip/hip_runtime.h>

typedef __bf16 bf16;
typedef __bf16 bf16x8 __attribute__((ext_vector_type(8)));
typedef float f32x4 __attribute__((ext_vector_type(4)));

#define B_ 2
#define C_ 512
#define HW_ 2304
#define GROUPS_ 32
#define CPG_ 16
#define EPS_ 1e-5f
#define THR_ 6.0f

// ---------------------------------------------------------------- gn stats
__global__ __launch_bounds__(256) void gn_stats_k(const float* __restrict__ x,
                                                  float* __restrict__ mean,
                                                  float* __restrict__ rstd) {
  int bg = blockIdx.x;  // b*32+g  (16 contiguous channels per group)
  const float4* p = (const float4*)(x + (long)bg * CPG_ * HW_);
  const int n4 = CPG_ * HW_ / 4;  // 9216
  float s = 0.f, ss = 0.f;
  for (int i = threadIdx.x; i < n4; i += 256) {
    float4 v = p[i];
    s += v.x + v.y + v.z + v.w;
    ss += v.x * v.x + v.y * v.y + v.z * v.z + v.w * v.w;
  }
#pragma unroll
  for (int d = 1; d < 64; d <<= 1) { s += __shfl_xor(s, d); ss += __shfl_xor(ss, d); }
  __shared__ float rs[4], rss[4];
  int wave = threadIdx.x >> 6, lane = threadIdx.x & 63;
  if (lane == 0) { rs[wave] = s; rss[wave] = ss; }
  __syncthreads();
  if (threadIdx.x == 0) {
    float S = rs[0] + rs[1] + rs[2] + rs[3];
    float SS = rss[0] + rss[1] + rss[2] + rss[3];
    float mu = S / (float)(CPG_ * HW_);
    float var = SS / (float)(CPG_ * HW_) - mu * mu;
    mean[bg] = mu;
    rstd[bg] = rsqrtf(var + EPS_);
  }
}

// ------------------------------------------------- gn apply + transpose->bf16
__global__ __launch_bounds__(256) void gn_apply_k(const float* __restrict__ x,
                                                  const float* __restrict__ gw,
                                                  const float* __restrict__ gb,
                                                  const float* __restrict__ mean,
                                                  const float* __restrict__ rstd,
                                                  bf16* __restrict__ xnT) {
  int n0 = blockIdx.x * 64, c0 = blockIdx.y * 32, b = blockIdx.z;
  int nn = n0 + (threadIdx.x & 63);
  int cb = c0 + ((threadIdx.x >> 6) << 3);
  bf16x8 o;
#pragma unroll
  for (int j = 0; j < 8; ++j) {
    int c = cb + j;
    int gi = b * GROUPS_ + (c >> 4);
    float sc = rstd[gi] * gw[c];
    float sh = gb[c] - mean[gi] * sc;
    float v = x[((long)b * C_ + c) * HW_ + nn];
    o[j] = (bf16)(v * sc + sh);
  }
  *(bf16x8*)&xnT[((long)b * HW_ + nn) * C_ + cb] = o;
}

// ------------------------------------------------------- weight prep (bf16)
__global__ __launch_bounds__(256) void prep_w_k(const float* __restrict__ qkv_w,
                                                const float* __restrict__ qkv_b,
                                                const float* __restrict__ proj_w,
                                                bf16* __restrict__ wqk,
                                                bf16* __restrict__ wv,
                                                bf16* __restrict__ wp,
                                                float* __restrict__ bqk,
                                                float* __restrict__ bv) {
  int idx = blockIdx.x * 256 + threadIdx.x;
  int r = idx >> 9, c = idx & 511;
  {
    int src = (r < 512) ? 3 * r : 3 * (r - 512) + 1;
    float sc = (r < 512) ? 0.125f : 1.0f;
    wqk[idx] = (bf16)(qkv_w[(long)src * 512 + c] * sc);
  }
  if (r < 512) {
    wv[idx] = (bf16)(qkv_w[(long)(3 * r + 2) * 512 + c]);
    wp[idx] = (bf16)(proj_w[idx]);
  }
  if (idx < 1024) {
    int src = (idx < 512) ? 3 * idx : 3 * (idx - 512) + 1;
    float sc = (idx < 512) ? 0.125f : 1.0f;
    bqk[idx] = qkv_b[src] * sc;
  }
  if (idx < 512) bv[idx] = qkv_b[3 * idx + 2];
}

// ------------------------------------------------------------ generic GEMM
template <int BIAS_MODE, bool RESID, typename OUT_T>
__global__ __launch_bounds__(256) void gemm_bt_k(const bf16* __restrict__ A,
                                                 const bf16* __restrict__ BT,
                                                 const float* __restrict__ bias,
                                                 const float* __restrict__ resid,
                                                 OUT_T* __restrict__ Cc,
                                                 int M, int N, int K,
                                                 long sA, long sBT, long sC) {
  int b = blockIdx.z;
  A += sA * b;
  BT += sBT * b;
  Cc += sC * b;
  const float* R = RESID ? (resid + sC * b) : nullptr;
  int m0 = blockIdx.y * 64, n0 = blockIdx.x * 64;
  int tid = threadIdx.x, lane = tid & 63, wave = tid >> 6;
  int wm = (wave >> 1) << 5, wn = (wave & 1) << 5;
  int fr = lane & 15, kg = (lane >> 4) << 3;
  __shared__ __align__(16) bf16 As[64][40];
  __shared__ __align__(16) bf16 Bs[64][40];
  int lr = tid >> 2, lk = (tid & 3) << 3;
  const bf16* ga = A + (long)(m0 + lr) * K + lk;
  const bf16* gbp = BT + (long)(n0 + lr) * K + lk;
  f32x4 acc[2][2] = {};
  for (int k0 = 0; k0 < K; k0 += 32) {
    __syncthreads();
    *(uint4*)&As[lr][lk] = *(const uint4*)(ga + k0);
    *(uint4*)&Bs[lr][lk] = *(const uint4*)(gbp + k0);
    __syncthreads();
    bf16x8 a0 = *(bf16x8*)&As[wm + fr][kg];
    bf16x8 a1 = *(bf16x8*)&As[wm + 16 + fr][kg];
    bf16x8 b0 = *(bf16x8*)&Bs[wn + fr][kg];
    bf16x8 b1 = *(bf16x8*)&Bs[wn + 16 + fr][kg];
    acc[0][0] = __builtin_amdgcn_mfma_f32_16x16x32_bf16(a0, b0, acc[0][0], 0, 0, 0);
    acc[0][1] = __builtin_amdgcn_mfma_f32_16x16x32_bf16(a0, b1, acc[0][1], 0, 0, 0);
    acc[1][0] = __builtin_amdgcn_mfma_f32_16x16x32_bf16(a1, b0, acc[1][0], 0, 0, 0);
    acc[1][1] = __builtin_amdgcn_mfma_f32_16x16x32_bf16(a1, b1, acc[1][1], 0, 0, 0);
  }
  int rbase = (lane >> 4) << 2;
#pragma unroll
  for (int mi = 0; mi < 2; ++mi)
#pragma unroll
    for (int nj = 0; nj < 2; ++nj)
#pragma unroll
      for (int reg = 0; reg < 4; ++reg) {
        int row = m0 + wm + (mi << 4) + rbase + reg;
        int col = n0 + wn + (nj << 4) + fr;
        float v = acc[mi][nj][reg];
        if (BIAS_MODE == 1) v += bias[row];
        if (BIAS_MODE == 2) v += bias[col];
        if (RESID) v += R[(long)row * N + col];
        Cc[(long)row * N + col] = (OUT_T)v;
      }
}

// ------------------------------------------------------------- attention
// yT[b][n][0:512)=q (prescaled), [512:1024)=k ; V[b][hd][n]
// k-split=2: partial Op (unnormalized, bf16) + Mp/Lp (f32) per split.
__global__ __launch_bounds__(256) void attn_k(const bf16* __restrict__ yT,
                                              const bf16* __restrict__ V,
                                              bf16* __restrict__ Op,
                                              float* __restrict__ Mp,
                                              float* __restrict__ Lp) {
  const int n = HW_;
  int bh = blockIdx.y, b = bh >> 3, h = bh & 7;
  int split = blockIdx.z;
  int q0 = blockIdx.x * 64;
  int kbeg = split * (n / 2);
  const int NT = (n / 2) / 64;  // 18
  int tid = threadIdx.x, lane = tid & 63, wave = tid >> 6;
  int fr = lane & 15, kg = (lane >> 4) << 3;
  int rbase = (lane >> 4) << 2;
  const bf16* yTb = yT + (long)b * n * 1024;
  const bf16* Vb = V + ((long)b * C_ + h * 64) * n;
  const bf16* Kb = yTb + 512 + h * 64;

  int qrow = q0 + (wave << 4) + fr;
  const bf16* qp = yTb + (long)qrow * 1024 + h * 64;
  bf16x8 qf0 = *(const bf16x8*)(qp + kg);
  bf16x8 qf1 = *(const bf16x8*)(qp + 32 + kg);

  __shared__ __align__(16) bf16 Kt[64][72];
  __shared__ __align__(16) bf16 Vt[64][72];
  __shared__ __align__(16) bf16 Pt[4][16][72];

  bf16x8 vone;
#pragma unroll
  for (int j = 0; j < 8; ++j) vone[j] = (bf16)1.0f;

  float m_run[4];
  f32x4 oacc[4] = {};
  f32x4 lacc = {};
#pragma unroll
  for (int r = 0; r < 4; ++r) m_run[r] = -3e38f;

  int r0 = tid >> 3, c0 = (tid & 7) << 3;  // staging: rows r0 and r0+32
  uint4 rk0, rk1, rv0, rv1;
  {
    long kr = (long)(kbeg + r0) * 1024;
    rk0 = *(const uint4*)&Kb[kr + c0];
    rk1 = *(const uint4*)&Kb[kr + 32 * 1024 + c0];
    rv0 = *(const uint4*)&Vb[(long)r0 * n + kbeg + c0];
    rv1 = *(const uint4*)&Vb[(long)(r0 + 32) * n + kbeg + c0];
  }

  for (int t = 0; t < NT; ++t) {
    *(uint4*)&Kt[r0][c0] = rk0;
    *(uint4*)&Kt[r0 + 32][c0] = rk1;
    *(uint4*)&Vt[r0][c0] = rv0;
    *(uint4*)&Vt[r0 + 32][c0] = rv1;
    if (t + 1 < NT) {
      int k0n = kbeg + (t + 1) * 64;
      long kr = (long)(k0n + r0) * 1024;
      rk0 = *(const uint4*)&Kb[kr + c0];
      rk1 = *(const uint4*)&Kb[kr + 32 * 1024 + c0];
      rv0 = *(const uint4*)&Vb[(long)r0 * n + k0n + c0];
      rv1 = *(const uint4*)&Vb[(long)(r0 + 32) * n + k0n + c0];
    }
    __syncthreads();
    // S = q @ k^T  (16 x 64 per wave)
    f32x4 s[4] = {};
#pragma unroll
    for (int nj = 0; nj < 4; ++nj) {
      bf16x8 kf0 = *(bf16x8*)&Kt[(nj << 4) + fr][kg];
      bf16x8 kf1 = *(bf16x8*)&Kt[(nj << 4) + fr][32 + kg];
      s[nj] = __builtin_amdgcn_mfma_f32_16x16x32_bf16(qf0, kf0, s[nj], 0, 0, 0);
      s[nj] = __builtin_amdgcn_mfma_f32_16x16x32_bf16(qf1, kf1, s[nj], 0, 0, 0);
    }
    float tmax[4];
#pragma unroll
    for (int r = 0; r < 4; ++r)
      tmax[r] = fmaxf(fmaxf(s[0][r], s[1][r]), fmaxf(s[2][r], s[3][r]));
#pragma unroll
    for (int d = 1; d < 16; d <<= 1)
#pragma unroll
      for (int r = 0; r < 4; ++r) tmax[r] = fmaxf(tmax[r], __shfl_xor(tmax[r], d));
    bool need = (tmax[0] > m_run[0] + THR_) || (tmax[1] > m_run[1] + THR_) ||
                (tmax[2] > m_run[2] + THR_) || (tmax[3] > m_run[3] + THR_);
    if (__any(need)) {
#pragma unroll
      for (int r = 0; r < 4; ++r) {
        float mn = fmaxf(m_run[r], tmax[r]);
        float corr = __expf(m_run[r] - mn);
        m_run[r] = mn;
#pragma unroll
        for (int dj = 0; dj < 4; ++dj) oacc[dj][r] *= corr;
        lacc[r] *= corr;
      }
    }
#pragma unroll
    for (int nj = 0; nj < 4; ++nj)
#pragma unroll
      for (int r = 0; r < 4; ++r) {
        float p = __expf(s[nj][r] - m_run[r]);
        Pt[wave][rbase + r][(nj << 4) + fr] = (bf16)p;
      }
    // O += P @ V ; row-sum via all-ones B operand (no barrier: Pt is per-wave)
    bf16x8 pf0 = *(bf16x8*)&Pt[wave][fr][kg];
    bf16x8 pf1 = *(bf16x8*)&Pt[wave][fr][32 + kg];
    lacc = __builtin_amdgcn_mfma_f32_16x16x32_bf16(pf0, vone, lacc, 0, 0, 0);
    lacc = __builtin_amdgcn_mfma_f32_16x16x32_bf16(pf1, vone, lacc, 0, 0, 0);
#pragma unroll
    for (int dj = 0; dj < 4; ++dj) {
      bf16x8 vf0 = *(bf16x8*)&Vt[(dj << 4) + fr][kg];
      bf16x8 vf1 = *(bf16x8*)&Vt[(dj << 4) + fr][32 + kg];
      oacc[dj] = __builtin_amdgcn_mfma_f32_16x16x32_bf16(pf0, vf0, oacc[dj], 0, 0, 0);
      oacc[dj] = __builtin_amdgcn_mfma_f32_16x16x32_bf16(pf1, vf1, oacc[dj], 0, 0, 0);
    }
    __syncthreads();
  }
  long base = (long)(split * 16 + bh) * n + q0 + (wave << 4);
#pragma unroll
  for (int dj = 0; dj < 4; ++dj)
#pragma unroll
    for (int r = 0; r < 4; ++r)
      Op[(base + rbase + r) * 64 + (dj << 4) + fr] = (bf16)oacc[dj][r];
  if (fr == 0) {
#pragma unroll
    for (int r = 0; r < 4; ++r) {
      Mp[base + rbase + r] = m_run[r];
      Lp[base + rbase + r] = lacc[r];
    }
  }
}

// ----------------------------------------------------------- split merge
__global__ __launch_bounds__(256) void attn_merge_k(const bf16* __restrict__ Op,
                                                    const float* __restrict__ Mp,
                                                    const float* __restrict__ Lp,
                                                    bf16* __restrict__ aT) {
  int bh = blockIdx.y, b = bh >> 3, h = bh & 7;
  int gi = blockIdx.x * 256 + threadIdx.x;
  int nrow = gi >> 3, dd8 = (gi & 7) << 3;
  long i0 = (long)bh * HW_ + nrow;
  long i1 = (long)(16 + bh) * HW_ + nrow;
  float m0 = Mp[i0], m1 = Mp[i1];
  float m = fmaxf(m0, m1);
  float e0 = __expf(m0 - m), e1 = __expf(m1 - m);
  float l = Lp[i0] * e0 + Lp[i1] * e1;
  float w0 = e0 / l, w1 = e1 / l;
  bf16x8 o0 = *(const bf16x8*)&Op[i0 * 64 + dd8];
  bf16x8 o1 = *(const bf16x8*)&Op[i1 * 64 + dd8];
  bf16x8 o;
#pragma unroll
  for (int j = 0; j < 8; ++j) o[j] = (bf16)((float)o0[j] * w0 + (float)o1[j] * w1);
  *(bf16x8*)&aT[((long)b * HW_ + nrow) * C_ + h * 64 + dd8] = o;
}

// ----------------------------------------------------------------- launch
extern "C" void kernel_launch(void* const* d_in, const int* in_sizes, int n_in,
                              void* d_out, int out_size, void* d_ws, size_t ws_size,
                              hipStream_t stream) {
  const float* x = (const float*)d_in[0];
  const float* gn_w = (const float*)d_in[1];
  const float* gn_b = (const float*)d_in[2];
  const float* qkv_w = (const float*)d_in[3];
  const float* qkv_b = (const float*)d_in[4];
  const float* proj_w = (const float*)d_in[5];
  const float* proj_b = (const float*)d_in[6];
  float* out = (float*)d_out;

  char* ws = (char*)d_ws;
  float* mean = (float*)ws; ws += 256;
  float* rstd = (float*)ws; ws += 256;
  float* bqk = (float*)ws;  ws += 4096;
  float* bv = (float*)ws;   ws += 2048;
  bf16* wqk = (bf16*)ws;    ws += 1024l * 512 * 2;
  bf16* wv = (bf16*)ws;     ws += 512l * 512 * 2;
  bf16* wp = (bf16*)ws;     ws += 512l * 512 * 2;
  bf16* xnT = (bf16*)ws;    ws += 2l * HW_ * 512 * 2;
  bf16* yT = (bf16*)ws;     ws += 2l * HW_ * 1024 * 2;
  bf16* v = (bf16*)ws;      ws += 2l * 512 * HW_ * 2;
  bf16* aT = (bf16*)ws;     ws += 2l * HW_ * 512 * 2;
  bf16* Op = (bf16*)ws;     ws += 2l * 16 * HW_ * 64 * 2;
  float* Mp = (float*)ws;   ws += 2l * 16 * HW_ * 4;
  float* Lp = (float*)ws;   ws += 2l * 16 * HW_ * 4;

  gn_stats_k<<<64, 256, 0, stream>>>(x, mean, rstd);
  prep_w_k<<<2048, 256, 0, stream>>>(qkv_w, qkv_b, proj_w, wqk, wv, wp, bqk, bv);
  gn_apply_k<<<dim3(36, 16, 2), 256, 0, stream>>>(x, gn_w, gn_b, mean, rstd, xnT);
  gemm_bt_k<2, false, bf16><<<dim3(16, 36, 2), 256, 0, stream>>>(
      xnT, wqk, bqk, nullptr, yT, 2304, 1024, 512, (long)HW_ * 512, 0, (long)HW_ * 1024);
  gemm_bt_k<1, false, bf16><<<dim3(36, 8, 2), 256, 0, stream>>>(
      wv, xnT, bv, nullptr, v, 512, 2304, 512, 0, (long)HW_ * 512, 512l * HW_);
  attn_k<<<dim3(36, 16, 2), 256, 0, stream>>>(yT, v, Op, Mp, Lp);
  attn_merge_k<<<dim3(72, 16), 256, 0, stream>>>(Op, Mp, Lp, aT);
  gemm_bt_k<1, true, float><<<dim3(36, 8, 2), 256, 0, stream>>>(
      wp, aT, proj_b, x, out, 512, 2304, 512, 0, (long)HW_ * 512, 512l * HW_);
}

// Round 3
// 115.014 us; speedup vs baseline: 1.4530x; 1.1641x over previous
//
#include <hip/hip_runtime.h>

typedef __bf16 bf16;
typedef __bf16 bf16x8 __attribute__((ext_vector_type(8)));
typedef __bf16 bf16x4 __attribute__((ext_vector_type(4)));
typedef float f32x4 __attribute__((ext_vector_type(4)));

#define B_ 2
#define C_ 512
#define HW_ 2304
#define GROUPS_ 32
#define CPG_ 16
#define EPS_ 1e-5f
#define THR_ 8.0f            // log2 units
#define LOG2E_ 1.44269504f
#define EXP2(x) __builtin_amdgcn_exp2f(x)

// ---------------------------------------------------------------- gn stats
__global__ __launch_bounds__(256) void gn_stats_k(const float* __restrict__ x,
                                                  float* __restrict__ mean,
                                                  float* __restrict__ rstd) {
  int bg = blockIdx.x;
  const float4* p = (const float4*)(x + (long)bg * CPG_ * HW_);
  const int n4 = CPG_ * HW_ / 4;
  float s = 0.f, ss = 0.f;
  for (int i = threadIdx.x; i < n4; i += 256) {
    float4 v = p[i];
    s += v.x + v.y + v.z + v.w;
    ss += v.x * v.x + v.y * v.y + v.z * v.z + v.w * v.w;
  }
#pragma unroll
  for (int d = 1; d < 64; d <<= 1) { s += __shfl_xor(s, d); ss += __shfl_xor(ss, d); }
  __shared__ float rs[4], rss[4];
  int wave = threadIdx.x >> 6, lane = threadIdx.x & 63;
  if (lane == 0) { rs[wave] = s; rss[wave] = ss; }
  __syncthreads();
  if (threadIdx.x == 0) {
    float S = rs[0] + rs[1] + rs[2] + rs[3];
    float SS = rss[0] + rss[1] + rss[2] + rss[3];
    float mu = S / (float)(CPG_ * HW_);
    float var = SS / (float)(CPG_ * HW_) - mu * mu;
    mean[bg] = mu;
    rstd[bg] = rsqrtf(var + EPS_);
  }
}

// ------------------------------------------------- gn apply + transpose->bf16
__global__ __launch_bounds__(256) void gn_apply_k(const float* __restrict__ x,
                                                  const float* __restrict__ gw,
                                                  const float* __restrict__ gb,
                                                  const float* __restrict__ mean,
                                                  const float* __restrict__ rstd,
                                                  bf16* __restrict__ xnT) {
  int n0 = blockIdx.x * 64, c0 = blockIdx.y * 32, b = blockIdx.z;
  int nn = n0 + (threadIdx.x & 63);
  int cb = c0 + ((threadIdx.x >> 6) << 3);
  bf16x8 o;
#pragma unroll
  for (int j = 0; j < 8; ++j) {
    int c = cb + j;
    int gi = b * GROUPS_ + (c >> 4);
    float sc = rstd[gi] * gw[c];
    float sh = gb[c] - mean[gi] * sc;
    float v = x[((long)b * C_ + c) * HW_ + nn];
    o[j] = (bf16)(v * sc + sh);
  }
  *(bf16x8*)&xnT[((long)b * HW_ + nn) * C_ + cb] = o;
}

// ------------------------------------------------------- weight prep (bf16)
// q rows scaled by 0.125*log2(e) so attention scores are in log2 units.
__global__ __launch_bounds__(256) void prep_w_k(const float* __restrict__ qkv_w,
                                                const float* __restrict__ qkv_b,
                                                const float* __restrict__ proj_w,
                                                bf16* __restrict__ wqk,
                                                bf16* __restrict__ wv,
                                                bf16* __restrict__ wp,
                                                float* __restrict__ bqk,
                                                float* __restrict__ bv) {
  int idx = blockIdx.x * 256 + threadIdx.x;
  int r = idx >> 9, c = idx & 511;
  {
    int src = (r < 512) ? 3 * r : 3 * (r - 512) + 1;
    float sc = (r < 512) ? 0.125f * LOG2E_ : 1.0f;
    wqk[idx] = (bf16)(qkv_w[(long)src * 512 + c] * sc);
  }
  if (r < 512) {
    wv[idx] = (bf16)(qkv_w[(long)(3 * r + 2) * 512 + c]);
    wp[idx] = (bf16)(proj_w[idx]);
  }
  if (idx < 1024) {
    int src = (idx < 512) ? 3 * idx : 3 * (idx - 512) + 1;
    float sc = (idx < 512) ? 0.125f * LOG2E_ : 1.0f;
    bqk[idx] = qkv_b[src] * sc;
  }
  if (idx < 512) bv[idx] = qkv_b[3 * idx + 2];
}

// ------------------------------------------------------------ generic GEMM
template <int BIAS_MODE, bool RESID, typename OUT_T>
__global__ __launch_bounds__(256) void gemm_bt_k(const bf16* __restrict__ A,
                                                 const bf16* __restrict__ BT,
                                                 const float* __restrict__ bias,
                                                 const float* __restrict__ resid,
                                                 OUT_T* __restrict__ Cc,
                                                 int M, int N, int K,
                                                 long sA, long sBT, long sC) {
  int b = blockIdx.z;
  A += sA * b;
  BT += sBT * b;
  Cc += sC * b;
  const float* R = RESID ? (resid + sC * b) : nullptr;
  int m0 = blockIdx.y * 64, n0 = blockIdx.x * 64;
  int tid = threadIdx.x, lane = tid & 63, wave = tid >> 6;
  int wm = (wave >> 1) << 5, wn = (wave & 1) << 5;
  int fr = lane & 15, kg = (lane >> 4) << 3;
  __shared__ __align__(16) bf16 As[64][40];
  __shared__ __align__(16) bf16 Bs[64][40];
  int lr = tid >> 2, lk = (tid & 3) << 3;
  const bf16* ga = A + (long)(m0 + lr) * K + lk;
  const bf16* gbp = BT + (long)(n0 + lr) * K + lk;
  f32x4 acc[2][2] = {};
  for (int k0 = 0; k0 < K; k0 += 32) {
    __syncthreads();
    *(uint4*)&As[lr][lk] = *(const uint4*)(ga + k0);
    *(uint4*)&Bs[lr][lk] = *(const uint4*)(gbp + k0);
    __syncthreads();
    bf16x8 a0 = *(bf16x8*)&As[wm + fr][kg];
    bf16x8 a1 = *(bf16x8*)&As[wm + 16 + fr][kg];
    bf16x8 b0 = *(bf16x8*)&Bs[wn + fr][kg];
    bf16x8 b1 = *(bf16x8*)&Bs[wn + 16 + fr][kg];
    acc[0][0] = __builtin_amdgcn_mfma_f32_16x16x32_bf16(a0, b0, acc[0][0], 0, 0, 0);
    acc[0][1] = __builtin_amdgcn_mfma_f32_16x16x32_bf16(a0, b1, acc[0][1], 0, 0, 0);
    acc[1][0] = __builtin_amdgcn_mfma_f32_16x16x32_bf16(a1, b0, acc[1][0], 0, 0, 0);
    acc[1][1] = __builtin_amdgcn_mfma_f32_16x16x32_bf16(a1, b1, acc[1][1], 0, 0, 0);
  }
  int rbase = (lane >> 4) << 2;
#pragma unroll
  for (int mi = 0; mi < 2; ++mi)
#pragma unroll
    for (int nj = 0; nj < 2; ++nj)
#pragma unroll
      for (int reg = 0; reg < 4; ++reg) {
        int row = m0 + wm + (mi << 4) + rbase + reg;
        int col = n0 + wn + (nj << 4) + fr;
        float v = acc[mi][nj][reg];
        if (BIAS_MODE == 1) v += bias[row];
        if (BIAS_MODE == 2) v += bias[col];
        if (RESID) v += R[(long)row * N + col];
        Cc[(long)row * N + col] = (OUT_T)v;
      }
}

// ------------------------------------------------------------- attention
// Swapped-operand flash attention: S^T = mfma(K, Q) puts a full q-row per lane.
// V staged into LDS with k-slot permutation slot(k) = (k&32)|((k&12)<<1)|((k&16)>>2)|(k&3)
// so the lane's exp'd S values ARE the PV B-fragment (k of P and V permuted identically).
__global__ __launch_bounds__(256) void attn_k(const bf16* __restrict__ yT,
                                              const bf16* __restrict__ V,
                                              bf16* __restrict__ Op,
                                              float* __restrict__ Mp,
                                              float* __restrict__ Lp) {
  const int n = HW_;
  int bh = blockIdx.y, b = bh >> 3, h = bh & 7;
  int split = blockIdx.z;
  int q0 = blockIdx.x * 64;
  int kbeg = split * (n / 2);
  const int NT = (n / 2) / 64;  // 18
  int tid = threadIdx.x, lane = tid & 63, wave = tid >> 6;
  int fr = lane & 15, g = lane >> 4, kg = g << 3;
  const bf16* yTb = yT + (long)b * n * 1024;
  const bf16* Vb = V + ((long)b * C_ + h * 64) * n;
  const bf16* Kb = yTb + 512 + h * 64;

  // Q fragment (B-operand): lane(fr,g) holds Q[q=fr][d=8g..8g+7] for wave's 16 rows
  int qrow = q0 + (wave << 4) + fr;
  const bf16* qp = yTb + (long)qrow * 1024 + h * 64;
  bf16x8 qf0 = *(const bf16x8*)(qp + kg);
  bf16x8 qf1 = *(const bf16x8*)(qp + 32 + kg);

  __shared__ __align__(16) bf16 Kt[64][72];  // [k][d]
  __shared__ __align__(16) bf16 Vt[64][72];  // [d][slot(k)]

  float m_run = -1e30f, l_run = 0.f;
  f32x4 oacc[4] = {};

  int r0 = tid >> 3;              // staging row (and +32)
  int c0e = (tid & 7) << 3;       // 8-element chunk
  int vs = (c0e & 32) | ((c0e & 8) << 1) | ((c0e & 16) >> 2);  // slot of k=c0e

  const bf16* kptr = Kb + (long)(kbeg + r0) * 1024 + c0e;
  const bf16* vptr = Vb + (long)r0 * n + kbeg + c0e;
  uint4 rk0 = *(const uint4*)kptr;
  uint4 rk1 = *(const uint4*)(kptr + 32 * 1024);
  uint4 rv0 = *(const uint4*)vptr;
  uint4 rv1 = *(const uint4*)(vptr + 32 * n);
  kptr += 64 * 1024;
  vptr += 64;

  for (int t = 0; t < NT; ++t) {
    *(uint4*)&Kt[r0][c0e] = rk0;
    *(uint4*)&Kt[r0 + 32][c0e] = rk1;
    // V: chunk k=c0e..c0e+3 -> slot vs; k=c0e+4..+7 -> slot vs+8
    *(uint2*)&Vt[r0][vs] = make_uint2(rv0.x, rv0.y);
    *(uint2*)&Vt[r0][vs + 8] = make_uint2(rv0.z, rv0.w);
    *(uint2*)&Vt[r0 + 32][vs] = make_uint2(rv1.x, rv1.y);
    *(uint2*)&Vt[r0 + 32][vs + 8] = make_uint2(rv1.z, rv1.w);
    if (t + 1 < NT) {
      rk0 = *(const uint4*)kptr;
      rk1 = *(const uint4*)(kptr + 32 * 1024);
      rv0 = *(const uint4*)vptr;
      rv1 = *(const uint4*)(vptr + 32 * n);
      kptr += 64 * 1024;
      vptr += 64;
    }
    __syncthreads();
    // S^T = K @ Q^T: s[nj][r] = S[k = nj*16 + 4g + r][q = fr]
    f32x4 s[4] = {};
#pragma unroll
    for (int nj = 0; nj < 4; ++nj) {
      bf16x8 kf0 = *(bf16x8*)&Kt[(nj << 4) + fr][kg];
      bf16x8 kf1 = *(bf16x8*)&Kt[(nj << 4) + fr][32 + kg];
      s[nj] = __builtin_amdgcn_mfma_f32_16x16x32_bf16(kf0, qf0, s[nj], 0, 0, 0);
      s[nj] = __builtin_amdgcn_mfma_f32_16x16x32_bf16(kf1, qf1, s[nj], 0, 0, 0);
    }
    // lane-local row max (16 vals) + 2 shuffles across the 4 lane-groups
    float pm = fmaxf(fmaxf(s[0][0], s[0][1]), fmaxf(s[0][2], s[0][3]));
#pragma unroll
    for (int nj = 1; nj < 4; ++nj)
      pm = fmaxf(pm, fmaxf(fmaxf(s[nj][0], s[nj][1]), fmaxf(s[nj][2], s[nj][3])));
    pm = fmaxf(pm, __shfl_xor(pm, 16));
    pm = fmaxf(pm, __shfl_xor(pm, 32));
    if (__any(pm > m_run + THR_)) {  // defer-max: skip rescale for small growth
      float mn = fmaxf(m_run, pm);
      float corr = EXP2(m_run - mn);
      m_run = mn;
      l_run *= corr;
#pragma unroll
      for (int dj = 0; dj < 4; ++dj)
#pragma unroll
        for (int r = 0; r < 4; ++r) oacc[dj][r] *= corr;
    }
    // exp (log2 units), row-sum, and direct PV B-fragment build
    float ls = 0.f;
    bf16x8 pa0, pa1;
#pragma unroll
    for (int r = 0; r < 4; ++r) {
      float p0 = EXP2(s[0][r] - m_run);
      float p1 = EXP2(s[1][r] - m_run);
      float p2 = EXP2(s[2][r] - m_run);
      float p3 = EXP2(s[3][r] - m_run);
      ls += (p0 + p1) + (p2 + p3);
      pa0[r] = (bf16)p0;
      pa0[4 + r] = (bf16)p1;
      pa1[r] = (bf16)p2;
      pa1[4 + r] = (bf16)p3;
    }
    ls += __shfl_xor(ls, 16);
    ls += __shfl_xor(ls, 32);
    l_run += ls;
    // O^T += V^T @ P : A = Vt rows (slot-permuted), B = pa
#pragma unroll
    for (int dj = 0; dj < 4; ++dj) {
      bf16x8 vf0 = *(bf16x8*)&Vt[(dj << 4) + fr][kg];
      bf16x8 vf1 = *(bf16x8*)&Vt[(dj << 4) + fr][32 + kg];
      oacc[dj] = __builtin_amdgcn_mfma_f32_16x16x32_bf16(vf0, pa0, oacc[dj], 0, 0, 0);
      oacc[dj] = __builtin_amdgcn_mfma_f32_16x16x32_bf16(vf1, pa1, oacc[dj], 0, 0, 0);
    }
    __syncthreads();
  }
  // oacc[dj][r] = O^T[d = dj*16 + 4g + r][q = fr]
  long orow = (long)(split * 16 + bh) * n + q0 + (wave << 4) + fr;
#pragma unroll
  for (int dj = 0; dj < 4; ++dj) {
    bf16x4 ov = {(bf16)oacc[dj][0], (bf16)oacc[dj][1], (bf16)oacc[dj][2], (bf16)oacc[dj][3]};
    *(bf16x4*)&Op[orow * 64 + (dj << 4) + (g << 2)] = ov;
  }
  if (g == 0) {
    Mp[orow] = m_run;
    Lp[orow] = l_run;
  }
}

// ----------------------------------------------------------- split merge
__global__ __launch_bounds__(256) void attn_merge_k(const bf16* __restrict__ Op,
                                                    const float* __restrict__ Mp,
                                                    const float* __restrict__ Lp,
                                                    bf16* __restrict__ aT) {
  int bh = blockIdx.y, b = bh >> 3, h = bh & 7;
  int gi = blockIdx.x * 256 + threadIdx.x;
  int nrow = gi >> 3, dd8 = (gi & 7) << 3;
  long i0 = (long)bh * HW_ + nrow;
  long i1 = (long)(16 + bh) * HW_ + nrow;
  float m0 = Mp[i0], m1 = Mp[i1];
  float m = fmaxf(m0, m1);
  float e0 = EXP2(m0 - m), e1 = EXP2(m1 - m);
  float l = Lp[i0] * e0 + Lp[i1] * e1;
  float w0 = e0 / l, w1 = e1 / l;
  bf16x8 o0 = *(const bf16x8*)&Op[i0 * 64 + dd8];
  bf16x8 o1 = *(const bf16x8*)&Op[i1 * 64 + dd8];
  bf16x8 o;
#pragma unroll
  for (int j = 0; j < 8; ++j) o[j] = (bf16)((float)o0[j] * w0 + (float)o1[j] * w1);
  *(bf16x8*)&aT[((long)b * HW_ + nrow) * C_ + h * 64 + dd8] = o;
}

// ----------------------------------------------------------------- launch
extern "C" void kernel_launch(void* const* d_in, const int* in_sizes, int n_in,
                              void* d_out, int out_size, void* d_ws, size_t ws_size,
                              hipStream_t stream) {
  const float* x = (const float*)d_in[0];
  const float* gn_w = (const float*)d_in[1];
  const float* gn_b = (const float*)d_in[2];
  const float* qkv_w = (const float*)d_in[3];
  const float* qkv_b = (const float*)d_in[4];
  const float* proj_w = (const float*)d_in[5];
  const float* proj_b = (const float*)d_in[6];
  float* out = (float*)d_out;

  char* ws = (char*)d_ws;
  float* mean = (float*)ws; ws += 256;
  float* rstd = (float*)ws; ws += 256;
  float* bqk = (float*)ws;  ws += 4096;
  float* bv = (float*)ws;   ws += 2048;
  bf16* wqk = (bf16*)ws;    ws += 1024l * 512 * 2;
  bf16* wv = (bf16*)ws;     ws += 512l * 512 * 2;
  bf16* wp = (bf16*)ws;     ws += 512l * 512 * 2;
  bf16* xnT = (bf16*)ws;    ws += 2l * HW_ * 512 * 2;
  bf16* yT = (bf16*)ws;     ws += 2l * HW_ * 1024 * 2;
  bf16* v = (bf16*)ws;      ws += 2l * 512 * HW_ * 2;
  bf16* aT = (bf16*)ws;     ws += 2l * HW_ * 512 * 2;
  bf16* Op = (bf16*)ws;     ws += 2l * 16 * HW_ * 64 * 2;
  float* Mp = (float*)ws;   ws += 2l * 16 * HW_ * 4;
  float* Lp = (float*)ws;   ws += 2l * 16 * HW_ * 4;

  gn_stats_k<<<64, 256, 0, stream>>>(x, mean, rstd);
  prep_w_k<<<2048, 256, 0, stream>>>(qkv_w, qkv_b, proj_w, wqk, wv, wp, bqk, bv);
  gn_apply_k<<<dim3(36, 16, 2), 256, 0, stream>>>(x, gn_w, gn_b, mean, rstd, xnT);
  gemm_bt_k<2, false, bf16><<<dim3(16, 36, 2), 256, 0, stream>>>(
      xnT, wqk, bqk, nullptr, yT, 2304, 1024, 512, (long)HW_ * 512, 0, (long)HW_ * 1024);
  gemm_bt_k<1, false, bf16><<<dim3(36, 8, 2), 256, 0, stream>>>(
      wv, xnT, bv, nullptr, v, 512, 2304, 512, 0, (long)HW_ * 512, 512l * HW_);
  attn_k<<<dim3(36, 16, 2), 256, 0, stream>>>(yT, v, Op, Mp, Lp);
  attn_merge_k<<<dim3(72, 16), 256, 0, stream>>>(Op, Mp, Lp, aT);
  gemm_bt_k<1, true, float><<<dim3(36, 8, 2), 256, 0, stream>>>(
      wp, aT, proj_b, x, out, 512, 2304, 512, 0, (long)HW_ * 512, 512l * HW_);
}

// Round 4
// 112.696 us; speedup vs baseline: 1.4829x; 1.0206x over previous
//
#include <hip/hip_runtime.h>

typedef __bf16 bf16;
typedef __bf16 bf16x8 __attribute__((ext_vector_type(8)));
typedef __bf16 bf16x4 __attribute__((ext_vector_type(4)));
typedef float f32x4 __attribute__((ext_vector_type(4)));

#define B_ 2
#define C_ 512
#define HW_ 2304
#define GROUPS_ 32
#define CPG_ 16
#define EPS_ 1e-5f
#define THR_ 8.0f            // log2 units
#define LOG2E_ 1.44269504f
#define EXP2(x) __builtin_amdgcn_exp2f(x)

// async global->LDS, 16B per lane; LDS dest must be linear in lane order.
__device__ __forceinline__ void gload_lds16(const bf16* g, bf16* l) {
  __builtin_amdgcn_global_load_lds((const __attribute__((address_space(1))) void*)g,
                                   (__attribute__((address_space(3))) void*)l, 16, 0, 0);
}

// ---------------------------------------------------------------- gn stats
__global__ __launch_bounds__(256) void gn_stats_k(const float* __restrict__ x,
                                                  float* __restrict__ mean,
                                                  float* __restrict__ rstd) {
  int bg = blockIdx.x;
  const float4* p = (const float4*)(x + (long)bg * CPG_ * HW_);
  const int n4 = CPG_ * HW_ / 4;
  float s = 0.f, ss = 0.f;
  for (int i = threadIdx.x; i < n4; i += 256) {
    float4 v = p[i];
    s += v.x + v.y + v.z + v.w;
    ss += v.x * v.x + v.y * v.y + v.z * v.z + v.w * v.w;
  }
#pragma unroll
  for (int d = 1; d < 64; d <<= 1) { s += __shfl_xor(s, d); ss += __shfl_xor(ss, d); }
  __shared__ float rs[4], rss[4];
  int wave = threadIdx.x >> 6, lane = threadIdx.x & 63;
  if (lane == 0) { rs[wave] = s; rss[wave] = ss; }
  __syncthreads();
  if (threadIdx.x == 0) {
    float S = rs[0] + rs[1] + rs[2] + rs[3];
    float SS = rss[0] + rss[1] + rss[2] + rss[3];
    float mu = S / (float)(CPG_ * HW_);
    float var = SS / (float)(CPG_ * HW_) - mu * mu;
    mean[bg] = mu;
    rstd[bg] = rsqrtf(var + EPS_);
  }
}

// ------------------------------------------------- gn apply + transpose->bf16
__global__ __launch_bounds__(256) void gn_apply_k(const float* __restrict__ x,
                                                  const float* __restrict__ gw,
                                                  const float* __restrict__ gb,
                                                  const float* __restrict__ mean,
                                                  const float* __restrict__ rstd,
                                                  bf16* __restrict__ xnT) {
  int n0 = blockIdx.x * 64, c0 = blockIdx.y * 32, b = blockIdx.z;
  int nn = n0 + (threadIdx.x & 63);
  int cb = c0 + ((threadIdx.x >> 6) << 3);
  bf16x8 o;
#pragma unroll
  for (int j = 0; j < 8; ++j) {
    int c = cb + j;
    int gi = b * GROUPS_ + (c >> 4);
    float sc = rstd[gi] * gw[c];
    float sh = gb[c] - mean[gi] * sc;
    float v = x[((long)b * C_ + c) * HW_ + nn];
    o[j] = (bf16)(v * sc + sh);
  }
  *(bf16x8*)&xnT[((long)b * HW_ + nn) * C_ + cb] = o;
}

// ------------------------------------------------------- weight prep (bf16)
__global__ __launch_bounds__(256) void prep_w_k(const float* __restrict__ qkv_w,
                                                const float* __restrict__ qkv_b,
                                                const float* __restrict__ proj_w,
                                                bf16* __restrict__ wqk,
                                                bf16* __restrict__ wv,
                                                bf16* __restrict__ wp,
                                                float* __restrict__ bqk,
                                                float* __restrict__ bv) {
  int idx = blockIdx.x * 256 + threadIdx.x;
  int r = idx >> 9, c = idx & 511;
  {
    int src = (r < 512) ? 3 * r : 3 * (r - 512) + 1;
    float sc = (r < 512) ? 0.125f * LOG2E_ : 1.0f;
    wqk[idx] = (bf16)(qkv_w[(long)src * 512 + c] * sc);
  }
  if (r < 512) {
    wv[idx] = (bf16)(qkv_w[(long)(3 * r + 2) * 512 + c]);
    wp[idx] = (bf16)(proj_w[idx]);
  }
  if (idx < 1024) {
    int src = (idx < 512) ? 3 * idx : 3 * (idx - 512) + 1;
    float sc = (idx < 512) ? 0.125f * LOG2E_ : 1.0f;
    bqk[idx] = qkv_b[src] * sc;
  }
  if (idx < 512) bv[idx] = qkv_b[3 * idx + 2];
}

// ------------------------------------------------------------ GEMM 128x64
// C[M][N] = A(MxK rm) * BT(NxK rm)^T. 4 waves (2x2 of 64x32), BK=32,
// global_load_lds staging, double-buffered LDS, 1 barrier per K-step.
template <int BIAS_MODE, bool RESID, typename OUT_T>
__global__ __launch_bounds__(256) void gemm_k(const bf16* __restrict__ A,
                                              const bf16* __restrict__ BT,
                                              const float* __restrict__ bias,
                                              const float* __restrict__ resid,
                                              OUT_T* __restrict__ Cc,
                                              int M, int N, int K,
                                              long sA, long sBT, long sC) {
  int b = blockIdx.z;
  A += sA * b;
  BT += sBT * b;
  Cc += sC * b;
  const float* R = RESID ? (resid + sC * b) : nullptr;
  int m0 = blockIdx.y * 128, n0 = blockIdx.x * 64;
  int tid = threadIdx.x, lane = tid & 63, wave = tid >> 6;
  int wm = (wave >> 1) << 6, wn = (wave & 1) << 5;
  int fr = lane & 15, kg = (lane >> 4) << 3;
  __shared__ __align__(16) bf16 As[2][128 * 32];
  __shared__ __align__(16) bf16 Bs[2][64 * 32];
  int sr = tid >> 2, sc = (tid & 3) << 3;
  const bf16* gA = A + (long)(m0 + sr) * K + sc;
  const bf16* gB = BT + (long)(n0 + sr) * K + sc;
  f32x4 acc[4][2] = {};
  const int NSTEP = K >> 5;  // 16
  // prologue: stage step 0 into buf 0
  gload_lds16(gA, &As[0][tid * 8]);
  gload_lds16(gA + (long)64 * K, &As[0][2048 + tid * 8]);
  gload_lds16(gB, &Bs[0][tid * 8]);
  __syncthreads();
  for (int t = 0; t < NSTEP; ++t) {
    int cur = t & 1;
    if (t + 1 < NSTEP) {
      int k0 = (t + 1) << 5;
      gload_lds16(gA + k0, &As[cur ^ 1][tid * 8]);
      gload_lds16(gA + (long)64 * K + k0, &As[cur ^ 1][2048 + tid * 8]);
      gload_lds16(gB + k0, &Bs[cur ^ 1][tid * 8]);
    }
    bf16x8 af[4], bfv[2];
#pragma unroll
    for (int mi = 0; mi < 4; ++mi)
      af[mi] = *(bf16x8*)&As[cur][(wm + (mi << 4) + fr) * 32 + kg];
#pragma unroll
    for (int nj = 0; nj < 2; ++nj)
      bfv[nj] = *(bf16x8*)&Bs[cur][(wn + (nj << 4) + fr) * 32 + kg];
#pragma unroll
    for (int mi = 0; mi < 4; ++mi)
#pragma unroll
      for (int nj = 0; nj < 2; ++nj)
        acc[mi][nj] = __builtin_amdgcn_mfma_f32_16x16x32_bf16(af[mi], bfv[nj], acc[mi][nj], 0, 0, 0);
    __syncthreads();
  }
  int rbase = (lane >> 4) << 2;
#pragma unroll
  for (int mi = 0; mi < 4; ++mi)
#pragma unroll
    for (int nj = 0; nj < 2; ++nj)
#pragma unroll
      for (int reg = 0; reg < 4; ++reg) {
        int row = m0 + wm + (mi << 4) + rbase + reg;
        int col = n0 + wn + (nj << 4) + fr;
        float v = acc[mi][nj][reg];
        if (BIAS_MODE == 1) v += bias[row];
        if (BIAS_MODE == 2) v += bias[col];
        if (RESID) v += R[(long)row * N + col];
        Cc[(long)row * N + col] = (OUT_T)v;
      }
}

// ------------------------------------------------------------- attention
// Swapped-operand flash attention, double-buffered K/V LDS, 1 barrier/tile.
__global__ __launch_bounds__(256) void attn_k(const bf16* __restrict__ yT,
                                              const bf16* __restrict__ V,
                                              bf16* __restrict__ Op,
                                              float* __restrict__ Mp,
                                              float* __restrict__ Lp) {
  const int n = HW_;
  int bh = blockIdx.y, b = bh >> 3, h = bh & 7;
  int split = blockIdx.z;
  int q0 = blockIdx.x * 64;
  int kbeg = split * (n / 2);
  const int NT = (n / 2) / 64;  // 18
  int tid = threadIdx.x, lane = tid & 63, wave = tid >> 6;
  int fr = lane & 15, g = lane >> 4, kg = g << 3;
  const bf16* yTb = yT + (long)b * n * 1024;
  const bf16* Vb = V + ((long)b * C_ + h * 64) * n;
  const bf16* Kb = yTb + 512 + h * 64;

  int qrow = q0 + (wave << 4) + fr;
  const bf16* qp = yTb + (long)qrow * 1024 + h * 64;
  bf16x8 qf0 = *(const bf16x8*)(qp + kg);
  bf16x8 qf1 = *(const bf16x8*)(qp + 32 + kg);

  __shared__ __align__(16) bf16 Kt[2][64][72];  // [buf][k][d]
  __shared__ __align__(16) bf16 Vt[2][64][72];  // [buf][d][slot(k)]

  float m_run = -1e30f, l_run = 0.f;
  f32x4 oacc[4] = {};

  int r0 = tid >> 3;
  int c0e = (tid & 7) << 3;
  int vs = (c0e & 32) | ((c0e & 8) << 1) | ((c0e & 16) >> 2);

  const bf16* kptr = Kb + (long)(kbeg + r0) * 1024 + c0e;
  const bf16* vptr = Vb + (long)r0 * n + kbeg + c0e;
  uint4 rk0 = *(const uint4*)kptr;
  uint4 rk1 = *(const uint4*)(kptr + 32 * 1024);
  uint4 rv0 = *(const uint4*)vptr;
  uint4 rv1 = *(const uint4*)(vptr + 32 * n);
  // write tile0 into buf0
  *(uint4*)&Kt[0][r0][c0e] = rk0;
  *(uint4*)&Kt[0][r0 + 32][c0e] = rk1;
  *(uint2*)&Vt[0][r0][vs] = make_uint2(rv0.x, rv0.y);
  *(uint2*)&Vt[0][r0][vs + 8] = make_uint2(rv0.z, rv0.w);
  *(uint2*)&Vt[0][r0 + 32][vs] = make_uint2(rv1.x, rv1.y);
  *(uint2*)&Vt[0][r0 + 32][vs + 8] = make_uint2(rv1.z, rv1.w);
  // prefetch tile1 into regs
  kptr += 64 * 1024;
  vptr += 64;
  rk0 = *(const uint4*)kptr;
  rk1 = *(const uint4*)(kptr + 32 * 1024);
  rv0 = *(const uint4*)vptr;
  rv1 = *(const uint4*)(vptr + 32 * n);
  __syncthreads();

  for (int t = 0; t < NT; ++t) {
    int cur = t & 1;
    // S^T = K @ Q^T
    f32x4 s[4] = {};
#pragma unroll
    for (int nj = 0; nj < 4; ++nj) {
      bf16x8 kf0 = *(bf16x8*)&Kt[cur][(nj << 4) + fr][kg];
      bf16x8 kf1 = *(bf16x8*)&Kt[cur][(nj << 4) + fr][32 + kg];
      s[nj] = __builtin_amdgcn_mfma_f32_16x16x32_bf16(kf0, qf0, s[nj], 0, 0, 0);
      s[nj] = __builtin_amdgcn_mfma_f32_16x16x32_bf16(kf1, qf1, s[nj], 0, 0, 0);
    }
    // write tile t+1 into the other buffer; prefetch t+2
    if (t + 1 < NT) {
      int nb = cur ^ 1;
      *(uint4*)&Kt[nb][r0][c0e] = rk0;
      *(uint4*)&Kt[nb][r0 + 32][c0e] = rk1;
      *(uint2*)&Vt[nb][r0][vs] = make_uint2(rv0.x, rv0.y);
      *(uint2*)&Vt[nb][r0][vs + 8] = make_uint2(rv0.z, rv0.w);
      *(uint2*)&Vt[nb][r0 + 32][vs] = make_uint2(rv1.x, rv1.y);
      *(uint2*)&Vt[nb][r0 + 32][vs + 8] = make_uint2(rv1.z, rv1.w);
      if (t + 2 < NT) {
        kptr += 64 * 1024;
        vptr += 64;
        rk0 = *(const uint4*)kptr;
        rk1 = *(const uint4*)(kptr + 32 * 1024);
        rv0 = *(const uint4*)vptr;
        rv1 = *(const uint4*)(vptr + 32 * n);
      }
    }
    // online softmax (lane-local rows)
    float pm = fmaxf(fmaxf(s[0][0], s[0][1]), fmaxf(s[0][2], s[0][3]));
#pragma unroll
    for (int nj = 1; nj < 4; ++nj)
      pm = fmaxf(pm, fmaxf(fmaxf(s[nj][0], s[nj][1]), fmaxf(s[nj][2], s[nj][3])));
    pm = fmaxf(pm, __shfl_xor(pm, 16));
    pm = fmaxf(pm, __shfl_xor(pm, 32));
    if (__any(pm > m_run + THR_)) {
      float mn = fmaxf(m_run, pm);
      float corr = EXP2(m_run - mn);
      m_run = mn;
      l_run *= corr;
#pragma unroll
      for (int dj = 0; dj < 4; ++dj)
#pragma unroll
        for (int r = 0; r < 4; ++r) oacc[dj][r] *= corr;
    }
    float ls = 0.f;
    bf16x8 pa0, pa1;
#pragma unroll
    for (int r = 0; r < 4; ++r) {
      float p0 = EXP2(s[0][r] - m_run);
      float p1 = EXP2(s[1][r] - m_run);
      float p2 = EXP2(s[2][r] - m_run);
      float p3 = EXP2(s[3][r] - m_run);
      ls += (p0 + p1) + (p2 + p3);
      pa0[r] = (bf16)p0;
      pa0[4 + r] = (bf16)p1;
      pa1[r] = (bf16)p2;
      pa1[4 + r] = (bf16)p3;
    }
    ls += __shfl_xor(ls, 16);
    ls += __shfl_xor(ls, 32);
    l_run += ls;
    // O^T += V^T @ P
#pragma unroll
    for (int dj = 0; dj < 4; ++dj) {
      bf16x8 vf0 = *(bf16x8*)&Vt[cur][(dj << 4) + fr][kg];
      bf16x8 vf1 = *(bf16x8*)&Vt[cur][(dj << 4) + fr][32 + kg];
      oacc[dj] = __builtin_amdgcn_mfma_f32_16x16x32_bf16(vf0, pa0, oacc[dj], 0, 0, 0);
      oacc[dj] = __builtin_amdgcn_mfma_f32_16x16x32_bf16(vf1, pa1, oacc[dj], 0, 0, 0);
    }
    __syncthreads();
  }
  long orow = (long)(split * 16 + bh) * n + q0 + (wave << 4) + fr;
#pragma unroll
  for (int dj = 0; dj < 4; ++dj) {
    bf16x4 ov = {(bf16)oacc[dj][0], (bf16)oacc[dj][1], (bf16)oacc[dj][2], (bf16)oacc[dj][3]};
    *(bf16x4*)&Op[orow * 64 + (dj << 4) + (g << 2)] = ov;
  }
  if (g == 0) {
    Mp[orow] = m_run;
    Lp[orow] = l_run;
  }
}

// ----------------------------------------------------------- split merge
__global__ __launch_bounds__(256) void attn_merge_k(const bf16* __restrict__ Op,
                                                    const float* __restrict__ Mp,
                                                    const float* __restrict__ Lp,
                                                    bf16* __restrict__ aT) {
  int bh = blockIdx.y, b = bh >> 3, h = bh & 7;
  int gi = blockIdx.x * 256 + threadIdx.x;
  int nrow = gi >> 3, dd8 = (gi & 7) << 3;
  long i0 = (long)bh * HW_ + nrow;
  long i1 = (long)(16 + bh) * HW_ + nrow;
  float m0 = Mp[i0], m1 = Mp[i1];
  float m = fmaxf(m0, m1);
  float e0 = EXP2(m0 - m), e1 = EXP2(m1 - m);
  float l = Lp[i0] * e0 + Lp[i1] * e1;
  float w0 = e0 / l, w1 = e1 / l;
  bf16x8 o0 = *(const bf16x8*)&Op[i0 * 64 + dd8];
  bf16x8 o1 = *(const bf16x8*)&Op[i1 * 64 + dd8];
  bf16x8 o;
#pragma unroll
  for (int j = 0; j < 8; ++j) o[j] = (bf16)((float)o0[j] * w0 + (float)o1[j] * w1);
  *(bf16x8*)&aT[((long)b * HW_ + nrow) * C_ + h * 64 + dd8] = o;
}

// ----------------------------------------------------------------- launch
extern "C" void kernel_launch(void* const* d_in, const int* in_sizes, int n_in,
                              void* d_out, int out_size, void* d_ws, size_t ws_size,
                              hipStream_t stream) {
  const float* x = (const float*)d_in[0];
  const float* gn_w = (const float*)d_in[1];
  const float* gn_b = (const float*)d_in[2];
  const float* qkv_w = (const float*)d_in[3];
  const float* qkv_b = (const float*)d_in[4];
  const float* proj_w = (const float*)d_in[5];
  const float* proj_b = (const float*)d_in[6];
  float* out = (float*)d_out;

  char* ws = (char*)d_ws;
  float* mean = (float*)ws; ws += 256;
  float* rstd = (float*)ws; ws += 256;
  float* bqk = (float*)ws;  ws += 4096;
  float* bv = (float*)ws;   ws += 2048;
  bf16* wqk = (bf16*)ws;    ws += 1024l * 512 * 2;
  bf16* wv = (bf16*)ws;     ws += 512l * 512 * 2;
  bf16* wp = (bf16*)ws;     ws += 512l * 512 * 2;
  bf16* xnT = (bf16*)ws;    ws += 2l * HW_ * 512 * 2;
  bf16* yT = (bf16*)ws;     ws += 2l * HW_ * 1024 * 2;
  bf16* v = (bf16*)ws;      ws += 2l * 512 * HW_ * 2;
  bf16* aT = (bf16*)ws;     ws += 2l * HW_ * 512 * 2;
  bf16* Op = (bf16*)ws;     ws += 2l * 16 * HW_ * 64 * 2;
  float* Mp = (float*)ws;   ws += 2l * 16 * HW_ * 4;
  float* Lp = (float*)ws;   ws += 2l * 16 * HW_ * 4;

  gn_stats_k<<<64, 256, 0, stream>>>(x, mean, rstd);
  prep_w_k<<<2048, 256, 0, stream>>>(qkv_w, qkv_b, proj_w, wqk, wv, wp, bqk, bv);
  gn_apply_k<<<dim3(36, 16, 2), 256, 0, stream>>>(x, gn_w, gn_b, mean, rstd, xnT);
  // yT[b][n][r] = xnT @ wqk^T + bqk   (M=2304, N=1024, K=512)
  gemm_k<2, false, bf16><<<dim3(16, 18, 2), 256, 0, stream>>>(
      xnT, wqk, bqk, nullptr, yT, 2304, 1024, 512, (long)HW_ * 512, 0, (long)HW_ * 1024);
  // v[b][hd][n] = wv @ xnT^T + bv     (M=512, N=2304, K=512)
  gemm_k<1, false, bf16><<<dim3(36, 4, 2), 256, 0, stream>>>(
      wv, xnT, bv, nullptr, v, 512, 2304, 512, 0, (long)HW_ * 512, 512l * HW_);
  attn_k<<<dim3(36, 16, 2), 256, 0, stream>>>(yT, v, Op, Mp, Lp);
  attn_merge_k<<<dim3(72, 16), 256, 0, stream>>>(Op, Mp, Lp, aT);
  // out = wp @ aT^T + proj_b + x      (M=512, N=2304, K=512), fp32 out
  gemm_k<1, true, float><<<dim3(36, 4, 2), 256, 0, stream>>>(
      wp, aT, proj_b, x, out, 512, 2304, 512, 0, (long)HW_ * 512, 512l * HW_);
}

// Round 6
// 106.433 us; speedup vs baseline: 1.5702x; 1.0588x over previous
//
#include <hip/hip_runtime.h>

typedef __bf16 bf16;
typedef __bf16 bf16x8 __attribute__((ext_vector_type(8)));
typedef __bf16 bf16x4 __attribute__((ext_vector_type(4)));
typedef float f32x4 __attribute__((ext_vector_type(4)));

#define B_ 2
#define C_ 512
#define HW_ 2304
#define GROUPS_ 32
#define CPG_ 16
#define EPS_ 1e-5f
#define THR_ 8.0f            // log2 units
#define LOG2E_ 1.44269504f
#define EXP2(x) __builtin_amdgcn_exp2f(x)

// async global->LDS, 16B per lane; LDS dest linear in lane order.
__device__ __forceinline__ void gload_lds16(const bf16* g, bf16* l) {
  __builtin_amdgcn_global_load_lds((const __attribute__((address_space(1))) void*)g,
                                   (__attribute__((address_space(3))) void*)l, 16, 0, 0);
}

// ---------------------------------------------------------------- gn stats
__global__ __launch_bounds__(256) void gn_stats_k(const float* __restrict__ x,
                                                  float* __restrict__ mean,
                                                  float* __restrict__ rstd) {
  int bg = blockIdx.x;
  const float4* p = (const float4*)(x + (long)bg * CPG_ * HW_);
  const int n4 = CPG_ * HW_ / 4;
  float s = 0.f, ss = 0.f;
  for (int i = threadIdx.x; i < n4; i += 256) {
    float4 v = p[i];
    s += v.x + v.y + v.z + v.w;
    ss += v.x * v.x + v.y * v.y + v.z * v.z + v.w * v.w;
  }
#pragma unroll
  for (int d = 1; d < 64; d <<= 1) { s += __shfl_xor(s, d); ss += __shfl_xor(ss, d); }
  __shared__ float rs[4], rss[4];
  int wave = threadIdx.x >> 6, lane = threadIdx.x & 63;
  if (lane == 0) { rs[wave] = s; rss[wave] = ss; }
  __syncthreads();
  if (threadIdx.x == 0) {
    float S = rs[0] + rs[1] + rs[2] + rs[3];
    float SS = rss[0] + rss[1] + rss[2] + rss[3];
    float mu = S / (float)(CPG_ * HW_);
    float var = SS / (float)(CPG_ * HW_) - mu * mu;
    mean[bg] = mu;
    rstd[bg] = rsqrtf(var + EPS_);
  }
}

// ------------------------------------------------- gn apply + transpose->bf16
__global__ __launch_bounds__(256) void gn_apply_k(const float* __restrict__ x,
                                                  const float* __restrict__ gw,
                                                  const float* __restrict__ gb,
                                                  const float* __restrict__ mean,
                                                  const float* __restrict__ rstd,
                                                  bf16* __restrict__ xnT) {
  int n0 = blockIdx.x * 64, c0 = blockIdx.y * 32, b = blockIdx.z;
  int nn = n0 + (threadIdx.x & 63);
  int cb = c0 + ((threadIdx.x >> 6) << 3);
  bf16x8 o;
#pragma unroll
  for (int j = 0; j < 8; ++j) {
    int c = cb + j;
    int gi = b * GROUPS_ + (c >> 4);
    float sc = rstd[gi] * gw[c];
    float sh = gb[c] - mean[gi] * sc;
    float v = x[((long)b * C_ + c) * HW_ + nn];
    o[j] = (bf16)(v * sc + sh);
  }
  *(bf16x8*)&xnT[((long)b * HW_ + nn) * C_ + cb] = o;
}

// ------------------------------------------------------- weight prep (bf16)
__global__ __launch_bounds__(256) void prep_w_k(const float* __restrict__ qkv_w,
                                                const float* __restrict__ qkv_b,
                                                const float* __restrict__ proj_w,
                                                bf16* __restrict__ wqk,
                                                bf16* __restrict__ wv,
                                                bf16* __restrict__ wp,
                                                float* __restrict__ bqk,
                                                float* __restrict__ bv) {
  int idx = blockIdx.x * 256 + threadIdx.x;
  int r = idx >> 9, c = idx & 511;
  {
    int src = (r < 512) ? 3 * r : 3 * (r - 512) + 1;
    float sc = (r < 512) ? 0.125f * LOG2E_ : 1.0f;
    wqk[idx] = (bf16)(qkv_w[(long)src * 512 + c] * sc);
  }
  if (r < 512) {
    wv[idx] = (bf16)(qkv_w[(long)(3 * r + 2) * 512 + c]);
    wp[idx] = (bf16)(proj_w[idx]);
  }
  if (idx < 1024) {
    int src = (idx < 512) ? 3 * idx : 3 * (idx - 512) + 1;
    float sc = (idx < 512) ? 0.125f * LOG2E_ : 1.0f;
    bqk[idx] = qkv_b[src] * sc;
  }
  if (idx < 512) bv[idx] = qkv_b[3 * idx + 2];
}

// ------------------------------------------------------------ GEMM 64x64
// C[M][N] = A(MxK rm) * BT(NxK rm)^T. 4 waves (2x2 of 32x32), BK=32,
// global_load_lds staging, double-buffered LDS, 1 barrier/K-step.
template <int BIAS_MODE, bool RESID, typename OUT_T>
__global__ __launch_bounds__(256) void gemm_k(const bf16* __restrict__ A,
                                              const bf16* __restrict__ BT,
                                              const float* __restrict__ bias,
                                              const float* __restrict__ resid,
                                              OUT_T* __restrict__ Cc,
                                              int M, int N, int K,
                                              long sA, long sBT, long sC) {
  int b = blockIdx.z;
  A += sA * b;
  BT += sBT * b;
  Cc += sC * b;
  const float* R = RESID ? (resid + sC * b) : nullptr;
  int m0 = blockIdx.y * 64, n0 = blockIdx.x * 64;
  int tid = threadIdx.x, lane = tid & 63, wave = tid >> 6;
  int wm = (wave >> 1) << 5, wn = (wave & 1) << 5;
  int fr = lane & 15, kg = (lane >> 4) << 3;
  __shared__ __align__(16) bf16 As[2][64 * 32];
  __shared__ __align__(16) bf16 Bs[2][64 * 32];
  int sr = tid >> 2, sc = (tid & 3) << 3;
  const bf16* gA = A + (long)(m0 + sr) * K + sc;
  const bf16* gB = BT + (long)(n0 + sr) * K + sc;
  f32x4 acc[2][2] = {};
  const int NSTEP = K >> 5;
  gload_lds16(gA, &As[0][tid * 8]);
  gload_lds16(gB, &Bs[0][tid * 8]);
  __syncthreads();
  for (int t = 0; t < NSTEP; ++t) {
    int cur = t & 1;
    if (t + 1 < NSTEP) {
      int k0 = (t + 1) << 5;
      gload_lds16(gA + k0, &As[cur ^ 1][tid * 8]);
      gload_lds16(gB + k0, &Bs[cur ^ 1][tid * 8]);
    }
    bf16x8 a0 = *(bf16x8*)&As[cur][(wm + fr) * 32 + kg];
    bf16x8 a1 = *(bf16x8*)&As[cur][(wm + 16 + fr) * 32 + kg];
    bf16x8 b0 = *(bf16x8*)&Bs[cur][(wn + fr) * 32 + kg];
    bf16x8 b1 = *(bf16x8*)&Bs[cur][(wn + 16 + fr) * 32 + kg];
    acc[0][0] = __builtin_amdgcn_mfma_f32_16x16x32_bf16(a0, b0, acc[0][0], 0, 0, 0);
    acc[0][1] = __builtin_amdgcn_mfma_f32_16x16x32_bf16(a0, b1, acc[0][1], 0, 0, 0);
    acc[1][0] = __builtin_amdgcn_mfma_f32_16x16x32_bf16(a1, b0, acc[1][0], 0, 0, 0);
    acc[1][1] = __builtin_amdgcn_mfma_f32_16x16x32_bf16(a1, b1, acc[1][1], 0, 0, 0);
    __syncthreads();
  }
  int rbase = (lane >> 4) << 2;
#pragma unroll
  for (int mi = 0; mi < 2; ++mi)
#pragma unroll
    for (int nj = 0; nj < 2; ++nj)
#pragma unroll
      for (int reg = 0; reg < 4; ++reg) {
        int row = m0 + wm + (mi << 4) + rbase + reg;
        int col = n0 + wn + (nj << 4) + fr;
        float v = acc[mi][nj][reg];
        if (BIAS_MODE == 1) v += bias[row];
        if (BIAS_MODE == 2) v += bias[col];
        if (RESID) v += R[(long)row * N + col];
        Cc[(long)row * N + col] = (OUT_T)v;
      }
}

// ------------------------------------------------------------- attention
// Swapped-operand flash attention. LDS tiles [64][64] (128B rows) with
// 16B-chunk rotation: phys_chunk = (logical_chunk + row) & 7, applied on
// BOTH write and read -> conflict-free b128 reads (8 slots x 8 lanes).
__global__ __launch_bounds__(256) void attn_k(const bf16* __restrict__ yT,
                                              const bf16* __restrict__ V,
                                              bf16* __restrict__ Op,
                                              float* __restrict__ Mp,
                                              float* __restrict__ Lp) {
  const int n = HW_;
  int bh = blockIdx.y, b = bh >> 3, h = bh & 7;
  int split = blockIdx.z;
  int q0 = blockIdx.x * 64;
  int kbeg = split * (n / 2);
  const int NT = (n / 2) / 64;  // 18
  int tid = threadIdx.x, lane = tid & 63, wave = tid >> 6;
  int fr = lane & 15, g = lane >> 4, kg = g << 3;
  const bf16* yTb = yT + (long)b * n * 1024;
  const bf16* Vb = V + ((long)b * C_ + h * 64) * n;
  const bf16* Kb = yTb + 512 + h * 64;

  int qrow = q0 + (wave << 4) + fr;
  const bf16* qp = yTb + (long)qrow * 1024 + h * 64;
  bf16x8 qf0 = *(const bf16x8*)(qp + kg);
  bf16x8 qf1 = *(const bf16x8*)(qp + 32 + kg);

  __shared__ __align__(16) bf16 Kt[2][64][64];  // [buf][k][rot(d)]
  __shared__ __align__(16) bf16 Vt[2][64][64];  // [buf][d][rot(slot(k))]

  // hoisted read offsets: row&7 == fr&7 for all fragment rows
  int o0 = ((g + fr) & 7) << 3;        // logical chunk g
  int o1 = ((4 + g + fr) & 7) << 3;    // logical chunk 4+g

  float m_run = -1e30f, l_run = 0.f;
  f32x4 oacc[4] = {};

  int r0 = tid >> 3;              // staging row (and +32); (r0+32)&7 == r0&7
  int ck = tid & 7;               // logical 16B chunk for K staging
  int c0e = ck << 3;
  int pk = ((ck + r0) & 7) << 3;  // K physical element offset
  // V slot permutation: chunk c0e covers slots S0..S0+3 and S0+8..S0+11
  int vs = (c0e & 32) | ((c0e & 8) << 1) | ((c0e & 16) >> 2);
  int cv = vs >> 3, sub = vs & 7;
  int pv0 = (((cv + r0) & 7) << 3) + sub;
  int pv1 = (((cv + 1 + r0) & 7) << 3) + sub;

  const bf16* kptr = Kb + (long)(kbeg + r0) * 1024 + c0e;
  const bf16* vptr = Vb + (long)r0 * n + kbeg + c0e;
  uint4 rk0 = *(const uint4*)kptr;
  uint4 rk1 = *(const uint4*)(kptr + 32 * 1024);
  uint4 rv0 = *(const uint4*)vptr;
  uint4 rv1 = *(const uint4*)(vptr + 32 * n);
  *(uint4*)&Kt[0][r0][pk] = rk0;
  *(uint4*)&Kt[0][r0 + 32][pk] = rk1;
  *(uint2*)&Vt[0][r0][pv0] = make_uint2(rv0.x, rv0.y);
  *(uint2*)&Vt[0][r0][pv1] = make_uint2(rv0.z, rv0.w);
  *(uint2*)&Vt[0][r0 + 32][pv0] = make_uint2(rv1.x, rv1.y);
  *(uint2*)&Vt[0][r0 + 32][pv1] = make_uint2(rv1.z, rv1.w);
  kptr += 64 * 1024;
  vptr += 64;
  rk0 = *(const uint4*)kptr;
  rk1 = *(const uint4*)(kptr + 32 * 1024);
  rv0 = *(const uint4*)vptr;
  rv1 = *(const uint4*)(vptr + 32 * n);
  __syncthreads();

  for (int t = 0; t < NT; ++t) {
    int cur = t & 1;
    // S^T = K @ Q^T
    f32x4 s[4] = {};
#pragma unroll
    for (int nj = 0; nj < 4; ++nj) {
      bf16x8 kf0 = *(bf16x8*)&Kt[cur][(nj << 4) + fr][o0];
      bf16x8 kf1 = *(bf16x8*)&Kt[cur][(nj << 4) + fr][o1];
      s[nj] = __builtin_amdgcn_mfma_f32_16x16x32_bf16(kf0, qf0, s[nj], 0, 0, 0);
      s[nj] = __builtin_amdgcn_mfma_f32_16x16x32_bf16(kf1, qf1, s[nj], 0, 0, 0);
    }
    if (t + 1 < NT) {
      int nb = cur ^ 1;
      *(uint4*)&Kt[nb][r0][pk] = rk0;
      *(uint4*)&Kt[nb][r0 + 32][pk] = rk1;
      *(uint2*)&Vt[nb][r0][pv0] = make_uint2(rv0.x, rv0.y);
      *(uint2*)&Vt[nb][r0][pv1] = make_uint2(rv0.z, rv0.w);
      *(uint2*)&Vt[nb][r0 + 32][pv0] = make_uint2(rv1.x, rv1.y);
      *(uint2*)&Vt[nb][r0 + 32][pv1] = make_uint2(rv1.z, rv1.w);
      if (t + 2 < NT) {
        kptr += 64 * 1024;
        vptr += 64;
        rk0 = *(const uint4*)kptr;
        rk1 = *(const uint4*)(kptr + 32 * 1024);
        rv0 = *(const uint4*)vptr;
        rv1 = *(const uint4*)(vptr + 32 * n);
      }
    }
    // online softmax (lane-local rows)
    float pm = fmaxf(fmaxf(s[0][0], s[0][1]), fmaxf(s[0][2], s[0][3]));
#pragma unroll
    for (int nj = 1; nj < 4; ++nj)
      pm = fmaxf(pm, fmaxf(fmaxf(s[nj][0], s[nj][1]), fmaxf(s[nj][2], s[nj][3])));
    pm = fmaxf(pm, __shfl_xor(pm, 16));
    pm = fmaxf(pm, __shfl_xor(pm, 32));
    if (__any(pm > m_run + THR_)) {
      float mn = fmaxf(m_run, pm);
      float corr = EXP2(m_run - mn);
      m_run = mn;
      l_run *= corr;
#pragma unroll
      for (int dj = 0; dj < 4; ++dj)
#pragma unroll
        for (int r = 0; r < 4; ++r) oacc[dj][r] *= corr;
    }
    float ls = 0.f;
    bf16x8 pa0, pa1;
#pragma unroll
    for (int r = 0; r < 4; ++r) {
      float p0 = EXP2(s[0][r] - m_run);
      float p1 = EXP2(s[1][r] - m_run);
      float p2 = EXP2(s[2][r] - m_run);
      float p3 = EXP2(s[3][r] - m_run);
      ls += (p0 + p1) + (p2 + p3);
      pa0[r] = (bf16)p0;
      pa0[4 + r] = (bf16)p1;
      pa1[r] = (bf16)p2;
      pa1[4 + r] = (bf16)p3;
    }
    ls += __shfl_xor(ls, 16);
    ls += __shfl_xor(ls, 32);
    l_run += ls;
    // O^T += V^T @ P
#pragma unroll
    for (int dj = 0; dj < 4; ++dj) {
      bf16x8 vf0 = *(bf16x8*)&Vt[cur][(dj << 4) + fr][o0];
      bf16x8 vf1 = *(bf16x8*)&Vt[cur][(dj << 4) + fr][o1];
      oacc[dj] = __builtin_amdgcn_mfma_f32_16x16x32_bf16(vf0, pa0, oacc[dj], 0, 0, 0);
      oacc[dj] = __builtin_amdgcn_mfma_f32_16x16x32_bf16(vf1, pa1, oacc[dj], 0, 0, 0);
    }
    __syncthreads();
  }
  long orow = (long)(split * 16 + bh) * n + q0 + (wave << 4) + fr;
#pragma unroll
  for (int dj = 0; dj < 4; ++dj) {
    bf16x4 ov = {(bf16)oacc[dj][0], (bf16)oacc[dj][1], (bf16)oacc[dj][2], (bf16)oacc[dj][3]};
    *(bf16x4*)&Op[orow * 64 + (dj << 4) + (g << 2)] = ov;
  }
  if (g == 0) {
    Mp[orow] = m_run;
    Lp[orow] = l_run;
  }
}

// ----------------------------------------------------------- split merge
__global__ __launch_bounds__(256) void attn_merge_k(const bf16* __restrict__ Op,
                                                    const float* __restrict__ Mp,
                                                    const float* __restrict__ Lp,
                                                    bf16* __restrict__ aT) {
  int bh = blockIdx.y, b = bh >> 3, h = bh & 7;
  int gi = blockIdx.x * 256 + threadIdx.x;
  int nrow = gi >> 3, dd8 = (gi & 7) << 3;
  long i0 = (long)bh * HW_ + nrow;
  long i1 = (long)(16 + bh) * HW_ + nrow;
  float m0 = Mp[i0], m1 = Mp[i1];
  float m = fmaxf(m0, m1);
  float e0 = EXP2(m0 - m), e1 = EXP2(m1 - m);
  float l = Lp[i0] * e0 + Lp[i1] * e1;
  float w0 = e0 / l, w1 = e1 / l;
  bf16x8 o0 = *(const bf16x8*)&Op[i0 * 64 + dd8];
  bf16x8 o1 = *(const bf16x8*)&Op[i1 * 64 + dd8];
  bf16x8 o;
#pragma unroll
  for (int j = 0; j < 8; ++j) o[j] = (bf16)((float)o0[j] * w0 + (float)o1[j] * w1);
  *(bf16x8*)&aT[((long)b * HW_ + nrow) * C_ + h * 64 + dd8] = o;
}

// ----------------------------------------------------------------- launch
extern "C" void kernel_launch(void* const* d_in, const int* in_sizes, int n_in,
                              void* d_out, int out_size, void* d_ws, size_t ws_size,
                              hipStream_t stream) {
  const float* x = (const float*)d_in[0];
  const float* gn_w = (const float*)d_in[1];
  const float* gn_b = (const float*)d_in[2];
  const float* qkv_w = (const float*)d_in[3];
  const float* qkv_b = (const float*)d_in[4];
  const float* proj_w = (const float*)d_in[5];
  const float* proj_b = (const float*)d_in[6];
  float* out = (float*)d_out;

  char* ws = (char*)d_ws;
  float* mean = (float*)ws; ws += 256;
  float* rstd = (float*)ws; ws += 256;
  float* bqk = (float*)ws;  ws += 4096;
  float* bv = (float*)ws;   ws += 2048;
  bf16* wqk = (bf16*)ws;    ws += 1024l * 512 * 2;
  bf16* wv = (bf16*)ws;     ws += 512l * 512 * 2;
  bf16* wp = (bf16*)ws;     ws += 512l * 512 * 2;
  bf16* xnT = (bf16*)ws;    ws += 2l * HW_ * 512 * 2;
  bf16* yT = (bf16*)ws;     ws += 2l * HW_ * 1024 * 2;
  bf16* v = (bf16*)ws;      ws += 2l * 512 * HW_ * 2;
  bf16* aT = (bf16*)ws;     ws += 2l * HW_ * 512 * 2;
  bf16* Op = (bf16*)ws;     ws += 2l * 16 * HW_ * 64 * 2;
  float* Mp = (float*)ws;   ws += 2l * 16 * HW_ * 4;
  float* Lp = (float*)ws;   ws += 2l * 16 * HW_ * 4;

  gn_stats_k<<<64, 256, 0, stream>>>(x, mean, rstd);
  prep_w_k<<<2048, 256, 0, stream>>>(qkv_w, qkv_b, proj_w, wqk, wv, wp, bqk, bv);
  gn_apply_k<<<dim3(36, 16, 2), 256, 0, stream>>>(x, gn_w, gn_b, mean, rstd, xnT);
  // yT[b][n][r] = xnT @ wqk^T + bqk   (M=2304, N=1024, K=512)
  gemm_k<2, false, bf16><<<dim3(16, 36, 2), 256, 0, stream>>>(
      xnT, wqk, bqk, nullptr, yT, 2304, 1024, 512, (long)HW_ * 512, 0, (long)HW_ * 1024);
  // v[b][hd][n] = wv @ xnT^T + bv     (M=512, N=2304, K=512)
  gemm_k<1, false, bf16><<<dim3(36, 8, 2), 256, 0, stream>>>(
      wv, xnT, bv, nullptr, v, 512, 2304, 512, 0, (long)HW_ * 512, 512l * HW_);
  attn_k<<<dim3(36, 16, 2), 256, 0, stream>>>(yT, v, Op, Mp, Lp);
  attn_merge_k<<<dim3(72, 16), 256, 0, stream>>>(Op, Mp, Lp, aT);
  // out = wp @ aT^T + proj_b + x      (M=512, N=2304, K=512), fp32 out
  gemm_k<1, true, float><<<dim3(36, 8, 2), 256, 0, stream>>>(
      wp, aT, proj_b, x, out, 512, 2304, 512, 0, (long)HW_ * 512, 512l * HW_);
}

// Round 7
// 95.672 us; speedup vs baseline: 1.7468x; 1.1125x over previous
//
#include <hip/hip_runtime.h>

typedef __bf16 bf16;
typedef __bf16 bf16x8 __attribute__((ext_vector_type(8)));
typedef __bf16 bf16x4 __attribute__((ext_vector_type(4)));
typedef float f32x4 __attribute__((ext_vector_type(4)));

#define B_ 2
#define C_ 512
#define HW_ 2304
#define GROUPS_ 32
#define CPG_ 16
#define EPS_ 1e-5f
#define THR_ 8.0f            // log2 units
#define LOG2E_ 1.44269504f
#define EXP2(x) __builtin_amdgcn_exp2f(x)

// async global->LDS, 16B per lane; LDS dest linear in lane order.
__device__ __forceinline__ void gload_lds16(const bf16* g, bf16* l) {
  __builtin_amdgcn_global_load_lds((const __attribute__((address_space(1))) void*)g,
                                   (__attribute__((address_space(3))) void*)l, 16, 0, 0);
}

// ------------------------------------------------- gn stats: partial sums
// 512 blocks: bg = blk>>3 (b*32+g), seg = blk&7. Each reduces 1/8 of a group.
__global__ __launch_bounds__(256) void gn_stats_part_k(const float* __restrict__ x,
                                                       float* __restrict__ ps,
                                                       float* __restrict__ pss) {
  int blk = blockIdx.x;
  int bg = blk >> 3, seg = blk & 7;
  const int n4 = CPG_ * HW_ / 4 / 8;  // 1152
  const float4* p = (const float4*)(x + (long)bg * CPG_ * HW_) + (long)seg * n4;
  float s = 0.f, ss = 0.f;
  for (int i = threadIdx.x; i < n4; i += 256) {
    float4 v = p[i];
    s += v.x + v.y + v.z + v.w;
    ss += v.x * v.x + v.y * v.y + v.z * v.z + v.w * v.w;
  }
#pragma unroll
  for (int d = 1; d < 64; d <<= 1) { s += __shfl_xor(s, d); ss += __shfl_xor(ss, d); }
  __shared__ float rs[4], rss[4];
  int wave = threadIdx.x >> 6, lane = threadIdx.x & 63;
  if (lane == 0) { rs[wave] = s; rss[wave] = ss; }
  __syncthreads();
  if (threadIdx.x == 0) {
    ps[blk] = rs[0] + rs[1] + rs[2] + rs[3];
    pss[blk] = rss[0] + rss[1] + rss[2] + rss[3];
  }
}

// ------------------- gn apply + transpose->bf16 (finalizes stats inline)
__global__ __launch_bounds__(256) void gn_apply_k(const float* __restrict__ x,
                                                  const float* __restrict__ gw,
                                                  const float* __restrict__ gb,
                                                  const float* __restrict__ ps,
                                                  const float* __restrict__ pss,
                                                  bf16* __restrict__ xnT) {
  int n0 = blockIdx.x * 64, c0 = blockIdx.y * 32, b = blockIdx.z;
  int nn = n0 + (threadIdx.x & 63);
  int cb = c0 + ((threadIdx.x >> 6) << 3);
  // this thread's 8 channels lie in one group (cb % 16 in {0,8})
  int gi = b * GROUPS_ + (cb >> 4);
  float s = 0.f, ss = 0.f;
#pragma unroll
  for (int k = 0; k < 8; ++k) { s += ps[gi * 8 + k]; ss += pss[gi * 8 + k]; }
  const float invN = 1.0f / (float)(CPG_ * HW_);
  float mu = s * invN;
  float var = ss * invN - mu * mu;
  float rstd = rsqrtf(var + EPS_);
  bf16x8 o;
#pragma unroll
  for (int j = 0; j < 8; ++j) {
    int c = cb + j;
    float sc = rstd * gw[c];
    float sh = gb[c] - mu * sc;
    float v = x[((long)b * C_ + c) * HW_ + nn];
    o[j] = (bf16)(v * sc + sh);
  }
  *(bf16x8*)&xnT[((long)b * HW_ + nn) * C_ + cb] = o;
}

// ------------------------------------------------------- weight prep (bf16)
__global__ __launch_bounds__(256) void prep_w_k(const float* __restrict__ qkv_w,
                                                const float* __restrict__ qkv_b,
                                                const float* __restrict__ proj_w,
                                                bf16* __restrict__ wqk,
                                                bf16* __restrict__ wv,
                                                bf16* __restrict__ wp,
                                                float* __restrict__ bqk,
                                                float* __restrict__ bv) {
  int idx = blockIdx.x * 256 + threadIdx.x;
  int r = idx >> 9, c = idx & 511;
  {
    int src = (r < 512) ? 3 * r : 3 * (r - 512) + 1;
    float sc = (r < 512) ? 0.125f * LOG2E_ : 1.0f;
    wqk[idx] = (bf16)(qkv_w[(long)src * 512 + c] * sc);
  }
  if (r < 512) {
    wv[idx] = (bf16)(qkv_w[(long)(3 * r + 2) * 512 + c]);
    wp[idx] = (bf16)(proj_w[idx]);
  }
  if (idx < 1024) {
    int src = (idx < 512) ? 3 * idx : 3 * (idx - 512) + 1;
    float sc = (idx < 512) ? 0.125f * LOG2E_ : 1.0f;
    bqk[idx] = qkv_b[src] * sc;
  }
  if (idx < 512) bv[idx] = qkv_b[3 * idx + 2];
}

// ------------------------------------------------------------ GEMM 64x64
template <int BIAS_MODE, bool RESID, typename OUT_T>
__global__ __launch_bounds__(256) void gemm_k(const bf16* __restrict__ A,
                                              const bf16* __restrict__ BT,
                                              const float* __restrict__ bias,
                                              const float* __restrict__ resid,
                                              OUT_T* __restrict__ Cc,
                                              int M, int N, int K,
                                              long sA, long sBT, long sC) {
  int b = blockIdx.z;
  A += sA * b;
  BT += sBT * b;
  Cc += sC * b;
  const float* R = RESID ? (resid + sC * b) : nullptr;
  int m0 = blockIdx.y * 64, n0 = blockIdx.x * 64;
  int tid = threadIdx.x, lane = tid & 63, wave = tid >> 6;
  int wm = (wave >> 1) << 5, wn = (wave & 1) << 5;
  int fr = lane & 15, kg = (lane >> 4) << 3;
  __shared__ __align__(16) bf16 As[2][64 * 32];
  __shared__ __align__(16) bf16 Bs[2][64 * 32];
  int sr = tid >> 2, sc = (tid & 3) << 3;
  const bf16* gA = A + (long)(m0 + sr) * K + sc;
  const bf16* gB = BT + (long)(n0 + sr) * K + sc;
  f32x4 acc[2][2] = {};
  const int NSTEP = K >> 5;
  gload_lds16(gA, &As[0][tid * 8]);
  gload_lds16(gB, &Bs[0][tid * 8]);
  __syncthreads();
  for (int t = 0; t < NSTEP; ++t) {
    int cur = t & 1;
    if (t + 1 < NSTEP) {
      int k0 = (t + 1) << 5;
      gload_lds16(gA + k0, &As[cur ^ 1][tid * 8]);
      gload_lds16(gB + k0, &Bs[cur ^ 1][tid * 8]);
    }
    bf16x8 a0 = *(bf16x8*)&As[cur][(wm + fr) * 32 + kg];
    bf16x8 a1 = *(bf16x8*)&As[cur][(wm + 16 + fr) * 32 + kg];
    bf16x8 b0 = *(bf16x8*)&Bs[cur][(wn + fr) * 32 + kg];
    bf16x8 b1 = *(bf16x8*)&Bs[cur][(wn + 16 + fr) * 32 + kg];
    acc[0][0] = __builtin_amdgcn_mfma_f32_16x16x32_bf16(a0, b0, acc[0][0], 0, 0, 0);
    acc[0][1] = __builtin_amdgcn_mfma_f32_16x16x32_bf16(a0, b1, acc[0][1], 0, 0, 0);
    acc[1][0] = __builtin_amdgcn_mfma_f32_16x16x32_bf16(a1, b0, acc[1][0], 0, 0, 0);
    acc[1][1] = __builtin_amdgcn_mfma_f32_16x16x32_bf16(a1, b1, acc[1][1], 0, 0, 0);
    __syncthreads();
  }
  int rbase = (lane >> 4) << 2;
#pragma unroll
  for (int mi = 0; mi < 2; ++mi)
#pragma unroll
    for (int nj = 0; nj < 2; ++nj)
#pragma unroll
      for (int reg = 0; reg < 4; ++reg) {
        int row = m0 + wm + (mi << 4) + rbase + reg;
        int col = n0 + wn + (nj << 4) + fr;
        float v = acc[mi][nj][reg];
        if (BIAS_MODE == 1) v += bias[row];
        if (BIAS_MODE == 2) v += bias[col];
        if (RESID) v += R[(long)row * N + col];
        Cc[(long)row * N + col] = (OUT_T)v;
      }
}

// ------------------------------------------------------------- attention
// Swapped-operand flash attention, 8 waves/block (128 q-rows), k-split=2.
// LDS tiles [64][64] with 16B-chunk rotation (conflict-free, verified r6).
__global__ __launch_bounds__(512) void attn_k(const bf16* __restrict__ yT,
                                              const bf16* __restrict__ V,
                                              bf16* __restrict__ Op,
                                              float* __restrict__ Mp,
                                              float* __restrict__ Lp) {
  const int n = HW_;
  int bh = blockIdx.y, b = bh >> 3, h = bh & 7;
  int split = blockIdx.z;
  int q0 = blockIdx.x * 128;
  int kbeg = split * (n / 2);
  const int NT = (n / 2) / 64;  // 18
  int tid = threadIdx.x, lane = tid & 63, wave = tid >> 6;
  int fr = lane & 15, g = lane >> 4, kg = g << 3;
  const bf16* yTb = yT + (long)b * n * 1024;
  const bf16* Vb = V + ((long)b * C_ + h * 64) * n;
  const bf16* Kb = yTb + 512 + h * 64;

  int qrow = q0 + (wave << 4) + fr;
  const bf16* qp = yTb + (long)qrow * 1024 + h * 64;
  bf16x8 qf0 = *(const bf16x8*)(qp + kg);
  bf16x8 qf1 = *(const bf16x8*)(qp + 32 + kg);

  __shared__ __align__(16) bf16 Kt[2][64][64];  // [buf][k][rot(d)]
  __shared__ __align__(16) bf16 Vt[2][64][64];  // [buf][d][rot(slot(k))]

  int o0 = ((g + fr) & 7) << 3;
  int o1 = ((4 + g + fr) & 7) << 3;

  float m_run = -1e30f, l_run = 0.f;
  f32x4 oacc[4] = {};

  int r0 = tid >> 3;              // 0..63: one staging row per lane
  int ck = tid & 7;
  int c0e = ck << 3;
  int pk = ((ck + r0) & 7) << 3;
  int vs = (c0e & 32) | ((c0e & 8) << 1) | ((c0e & 16) >> 2);
  int cv = vs >> 3, sub = vs & 7;
  int pv0 = (((cv + r0) & 7) << 3) + sub;
  int pv1 = (((cv + 1 + r0) & 7) << 3) + sub;

  const bf16* kptr = Kb + (long)(kbeg + r0) * 1024 + c0e;
  const bf16* vptr = Vb + (long)r0 * n + kbeg + c0e;
  uint4 rk = *(const uint4*)kptr;
  uint4 rv = *(const uint4*)vptr;
  *(uint4*)&Kt[0][r0][pk] = rk;
  *(uint2*)&Vt[0][r0][pv0] = make_uint2(rv.x, rv.y);
  *(uint2*)&Vt[0][r0][pv1] = make_uint2(rv.z, rv.w);
  kptr += 64 * 1024;
  vptr += 64;
  rk = *(const uint4*)kptr;
  rv = *(const uint4*)vptr;
  __syncthreads();

  for (int t = 0; t < NT; ++t) {
    int cur = t & 1;
    // S^T = K @ Q^T
    f32x4 s[4] = {};
#pragma unroll
    for (int nj = 0; nj < 4; ++nj) {
      bf16x8 kf0 = *(bf16x8*)&Kt[cur][(nj << 4) + fr][o0];
      bf16x8 kf1 = *(bf16x8*)&Kt[cur][(nj << 4) + fr][o1];
      s[nj] = __builtin_amdgcn_mfma_f32_16x16x32_bf16(kf0, qf0, s[nj], 0, 0, 0);
      s[nj] = __builtin_amdgcn_mfma_f32_16x16x32_bf16(kf1, qf1, s[nj], 0, 0, 0);
    }
    if (t + 1 < NT) {
      int nb = cur ^ 1;
      *(uint4*)&Kt[nb][r0][pk] = rk;
      *(uint2*)&Vt[nb][r0][pv0] = make_uint2(rv.x, rv.y);
      *(uint2*)&Vt[nb][r0][pv1] = make_uint2(rv.z, rv.w);
      if (t + 2 < NT) {
        kptr += 64 * 1024;
        vptr += 64;
        rk = *(const uint4*)kptr;
        rv = *(const uint4*)vptr;
      }
    }
    // online softmax (lane-local rows)
    float pm = fmaxf(fmaxf(s[0][0], s[0][1]), fmaxf(s[0][2], s[0][3]));
#pragma unroll
    for (int nj = 1; nj < 4; ++nj)
      pm = fmaxf(pm, fmaxf(fmaxf(s[nj][0], s[nj][1]), fmaxf(s[nj][2], s[nj][3])));
    pm = fmaxf(pm, __shfl_xor(pm, 16));
    pm = fmaxf(pm, __shfl_xor(pm, 32));
    if (__any(pm > m_run + THR_)) {
      float mn = fmaxf(m_run, pm);
      float corr = EXP2(m_run - mn);
      m_run = mn;
      l_run *= corr;
#pragma unroll
      for (int dj = 0; dj < 4; ++dj)
#pragma unroll
        for (int r = 0; r < 4; ++r) oacc[dj][r] *= corr;
    }
    float ls = 0.f;
    bf16x8 pa0, pa1;
#pragma unroll
    for (int r = 0; r < 4; ++r) {
      float p0 = EXP2(s[0][r] - m_run);
      float p1 = EXP2(s[1][r] - m_run);
      float p2 = EXP2(s[2][r] - m_run);
      float p3 = EXP2(s[3][r] - m_run);
      ls += (p0 + p1) + (p2 + p3);
      pa0[r] = (bf16)p0;
      pa0[4 + r] = (bf16)p1;
      pa1[r] = (bf16)p2;
      pa1[4 + r] = (bf16)p3;
    }
    ls += __shfl_xor(ls, 16);
    ls += __shfl_xor(ls, 32);
    l_run += ls;
    // O^T += V^T @ P
#pragma unroll
    for (int dj = 0; dj < 4; ++dj) {
      bf16x8 vf0 = *(bf16x8*)&Vt[cur][(dj << 4) + fr][o0];
      bf16x8 vf1 = *(bf16x8*)&Vt[cur][(dj << 4) + fr][o1];
      oacc[dj] = __builtin_amdgcn_mfma_f32_16x16x32_bf16(vf0, pa0, oacc[dj], 0, 0, 0);
      oacc[dj] = __builtin_amdgcn_mfma_f32_16x16x32_bf16(vf1, pa1, oacc[dj], 0, 0, 0);
    }
    __syncthreads();
  }
  long orow = (long)(split * 16 + bh) * n + q0 + (wave << 4) + fr;
#pragma unroll
  for (int dj = 0; dj < 4; ++dj) {
    bf16x4 ov = {(bf16)oacc[dj][0], (bf16)oacc[dj][1], (bf16)oacc[dj][2], (bf16)oacc[dj][3]};
    *(bf16x4*)&Op[orow * 64 + (dj << 4) + (g << 2)] = ov;
  }
  if (g == 0) {
    Mp[orow] = m_run;
    Lp[orow] = l_run;
  }
}

// ----------------------------------------------------------- split merge
__global__ __launch_bounds__(256) void attn_merge_k(const bf16* __restrict__ Op,
                                                    const float* __restrict__ Mp,
                                                    const float* __restrict__ Lp,
                                                    bf16* __restrict__ aT) {
  int bh = blockIdx.y, b = bh >> 3, h = bh & 7;
  int gi = blockIdx.x * 256 + threadIdx.x;
  int nrow = gi >> 3, dd8 = (gi & 7) << 3;
  long i0 = (long)bh * HW_ + nrow;
  long i1 = (long)(16 + bh) * HW_ + nrow;
  float m0 = Mp[i0], m1 = Mp[i1];
  float m = fmaxf(m0, m1);
  float e0 = EXP2(m0 - m), e1 = EXP2(m1 - m);
  float l = Lp[i0] * e0 + Lp[i1] * e1;
  float w0 = e0 / l, w1 = e1 / l;
  bf16x8 o0 = *(const bf16x8*)&Op[i0 * 64 + dd8];
  bf16x8 o1 = *(const bf16x8*)&Op[i1 * 64 + dd8];
  bf16x8 o;
#pragma unroll
  for (int j = 0; j < 8; ++j) o[j] = (bf16)((float)o0[j] * w0 + (float)o1[j] * w1);
  *(bf16x8*)&aT[((long)b * HW_ + nrow) * C_ + h * 64 + dd8] = o;
}

// ----------------------------------------------------------------- launch
extern "C" void kernel_launch(void* const* d_in, const int* in_sizes, int n_in,
                              void* d_out, int out_size, void* d_ws, size_t ws_size,
                              hipStream_t stream) {
  const float* x = (const float*)d_in[0];
  const float* gn_w = (const float*)d_in[1];
  const float* gn_b = (const float*)d_in[2];
  const float* qkv_w = (const float*)d_in[3];
  const float* qkv_b = (const float*)d_in[4];
  const float* proj_w = (const float*)d_in[5];
  const float* proj_b = (const float*)d_in[6];
  float* out = (float*)d_out;

  char* ws = (char*)d_ws;
  float* ps = (float*)ws;   ws += 2048;
  float* pss = (float*)ws;  ws += 2048;
  float* bqk = (float*)ws;  ws += 4096;
  float* bv = (float*)ws;   ws += 2048;
  bf16* wqk = (bf16*)ws;    ws += 1024l * 512 * 2;
  bf16* wv = (bf16*)ws;     ws += 512l * 512 * 2;
  bf16* wp = (bf16*)ws;     ws += 512l * 512 * 2;
  bf16* xnT = (bf16*)ws;    ws += 2l * HW_ * 512 * 2;
  bf16* yT = (bf16*)ws;     ws += 2l * HW_ * 1024 * 2;
  bf16* v = (bf16*)ws;      ws += 2l * 512 * HW_ * 2;
  bf16* aT = (bf16*)ws;     ws += 2l * HW_ * 512 * 2;
  bf16* Op = (bf16*)ws;     ws += 2l * 16 * HW_ * 64 * 2;
  float* Mp = (float*)ws;   ws += 2l * 16 * HW_ * 4;
  float* Lp = (float*)ws;   ws += 2l * 16 * HW_ * 4;

  gn_stats_part_k<<<512, 256, 0, stream>>>(x, ps, pss);
  prep_w_k<<<2048, 256, 0, stream>>>(qkv_w, qkv_b, proj_w, wqk, wv, wp, bqk, bv);
  gn_apply_k<<<dim3(36, 16, 2), 256, 0, stream>>>(x, gn_w, gn_b, ps, pss, xnT);
  // yT[b][n][r] = xnT @ wqk^T + bqk   (M=2304, N=1024, K=512)
  gemm_k<2, false, bf16><<<dim3(16, 36, 2), 256, 0, stream>>>(
      xnT, wqk, bqk, nullptr, yT, 2304, 1024, 512, (long)HW_ * 512, 0, (long)HW_ * 1024);
  // v[b][hd][n] = wv @ xnT^T + bv     (M=512, N=2304, K=512)
  gemm_k<1, false, bf16><<<dim3(36, 8, 2), 256, 0, stream>>>(
      wv, xnT, bv, nullptr, v, 512, 2304, 512, 0, (long)HW_ * 512, 512l * HW_);
  attn_k<<<dim3(18, 16, 2), 512, 0, stream>>>(yT, v, Op, Mp, Lp);
  attn_merge_k<<<dim3(72, 16), 256, 0, stream>>>(Op, Mp, Lp, aT);
  // out = wp @ aT^T + proj_b + x      (M=512, N=2304, K=512), fp32 out
  gemm_k<1, true, float><<<dim3(36, 8, 2), 256, 0, stream>>>(
      wp, aT, proj_b, x, out, 512, 2304, 512, 0, (long)HW_ * 512, 512l * HW_);
}

// Round 8
// 93.934 us; speedup vs baseline: 1.7791x; 1.0185x over previous
//
#include <hip/hip_runtime.h>

typedef __bf16 bf16;
typedef __bf16 bf16x8 __attribute__((ext_vector_type(8)));
typedef __bf16 bf16x4 __attribute__((ext_vector_type(4)));
typedef float f32x4 __attribute__((ext_vector_type(4)));

#define B_ 2
#define C_ 512
#define HW_ 2304
#define GROUPS_ 32
#define CPG_ 16
#define EPS_ 1e-5f
#define THR_ 8.0f            // log2 units
#define LOG2E_ 1.44269504f
#define EXP2(x) __builtin_amdgcn_exp2f(x)

// async global->LDS, 16B per lane; LDS dest linear in lane order.
__device__ __forceinline__ void gload_lds16(const bf16* g, bf16* l) {
  __builtin_amdgcn_global_load_lds((const __attribute__((address_space(1))) void*)g,
                                   (__attribute__((address_space(3))) void*)l, 16, 0, 0);
}

// ------------------------------------------------- gn stats: partial sums
__global__ __launch_bounds__(256) void gn_stats_part_k(const float* __restrict__ x,
                                                       float* __restrict__ ps,
                                                       float* __restrict__ pss) {
  int blk = blockIdx.x;
  int bg = blk >> 3, seg = blk & 7;
  const int n4 = CPG_ * HW_ / 4 / 8;  // 1152
  const float4* p = (const float4*)(x + (long)bg * CPG_ * HW_) + (long)seg * n4;
  float s = 0.f, ss = 0.f;
  for (int i = threadIdx.x; i < n4; i += 256) {
    float4 v = p[i];
    s += v.x + v.y + v.z + v.w;
    ss += v.x * v.x + v.y * v.y + v.z * v.z + v.w * v.w;
  }
#pragma unroll
  for (int d = 1; d < 64; d <<= 1) { s += __shfl_xor(s, d); ss += __shfl_xor(ss, d); }
  __shared__ float rs[4], rss[4];
  int wave = threadIdx.x >> 6, lane = threadIdx.x & 63;
  if (lane == 0) { rs[wave] = s; rss[wave] = ss; }
  __syncthreads();
  if (threadIdx.x == 0) {
    ps[blk] = rs[0] + rs[1] + rs[2] + rs[3];
    pss[blk] = rss[0] + rss[1] + rss[2] + rss[3];
  }
}

// ------------------- gn apply + transpose->bf16 (finalizes stats inline)
__global__ __launch_bounds__(256) void gn_apply_k(const float* __restrict__ x,
                                                  const float* __restrict__ gw,
                                                  const float* __restrict__ gb,
                                                  const float* __restrict__ ps,
                                                  const float* __restrict__ pss,
                                                  bf16* __restrict__ xnT) {
  int n0 = blockIdx.x * 64, c0 = blockIdx.y * 32, b = blockIdx.z;
  int nn = n0 + (threadIdx.x & 63);
  int cb = c0 + ((threadIdx.x >> 6) << 3);
  int gi = b * GROUPS_ + (cb >> 4);
  float s = 0.f, ss = 0.f;
#pragma unroll
  for (int k = 0; k < 8; ++k) { s += ps[gi * 8 + k]; ss += pss[gi * 8 + k]; }
  const float invN = 1.0f / (float)(CPG_ * HW_);
  float mu = s * invN;
  float var = ss * invN - mu * mu;
  float rstd = rsqrtf(var + EPS_);
  bf16x8 o;
#pragma unroll
  for (int j = 0; j < 8; ++j) {
    int c = cb + j;
    float sc = rstd * gw[c];
    float sh = gb[c] - mu * sc;
    float v = x[((long)b * C_ + c) * HW_ + nn];
    o[j] = (bf16)(v * sc + sh);
  }
  *(bf16x8*)&xnT[((long)b * HW_ + nn) * C_ + cb] = o;
}

// ------------------------------------------------------- weight prep (bf16)
__global__ __launch_bounds__(256) void prep_w_k(const float* __restrict__ qkv_w,
                                                const float* __restrict__ qkv_b,
                                                const float* __restrict__ proj_w,
                                                bf16* __restrict__ wqk,
                                                bf16* __restrict__ wv,
                                                bf16* __restrict__ wp,
                                                float* __restrict__ bqk,
                                                float* __restrict__ bv) {
  int idx = blockIdx.x * 256 + threadIdx.x;
  int r = idx >> 9, c = idx & 511;
  {
    int src = (r < 512) ? 3 * r : 3 * (r - 512) + 1;
    float sc = (r < 512) ? 0.125f * LOG2E_ : 1.0f;
    wqk[idx] = (bf16)(qkv_w[(long)src * 512 + c] * sc);
  }
  if (r < 512) {
    wv[idx] = (bf16)(qkv_w[(long)(3 * r + 2) * 512 + c]);
    wp[idx] = (bf16)(proj_w[idx]);
  }
  if (idx < 1024) {
    int src = (idx < 512) ? 3 * idx : 3 * (idx - 512) + 1;
    float sc = (idx < 512) ? 0.125f * LOG2E_ : 1.0f;
    bqk[idx] = qkv_b[src] * sc;
  }
  if (idx < 512) bv[idx] = qkv_b[3 * idx + 2];
}

// ------------------------------------------------------------ GEMM 64x64
// C[M][N] = A(MxK rm) * BT(NxK rm)^T, K=512 fixed. 4 waves (2x2 of 32x32),
// BK=32, triple-buffered gload_lds with prefetch distance 2 + counted vmcnt:
// loads issued at step t are consumed at t+2 -> HBM/L2 latency hidden under
// a full step of compute; never drains in-flight prefetch at the barrier.
template <int BIAS_MODE, bool RESID, typename OUT_T>
__global__ __launch_bounds__(256) void gemm_k(const bf16* __restrict__ A,
                                              const bf16* __restrict__ BT,
                                              const float* __restrict__ bias,
                                              const float* __restrict__ resid,
                                              OUT_T* __restrict__ Cc,
                                              int M, int N,
                                              long sA, long sBT, long sC) {
  constexpr int KK = 512;
  constexpr int NSTEP = KK >> 5;  // 16
  int b = blockIdx.z;
  A += sA * b;
  BT += sBT * b;
  Cc += sC * b;
  const float* R = RESID ? (resid + sC * b) : nullptr;
  int m0 = blockIdx.y * 64, n0 = blockIdx.x * 64;
  int tid = threadIdx.x, lane = tid & 63, wave = tid >> 6;
  int wm = (wave >> 1) << 5, wn = (wave & 1) << 5;
  int fr = lane & 15, kg = (lane >> 4) << 3;
  __shared__ __align__(16) bf16 As[3][64 * 32];
  __shared__ __align__(16) bf16 Bs[3][64 * 32];
  int sr = tid >> 2, sc = (tid & 3) << 3;
  const bf16* gA = A + (long)(m0 + sr) * KK + sc;
  const bf16* gB = BT + (long)(n0 + sr) * KK + sc;
  f32x4 acc[2][2] = {};
  // prologue: stage steps 0 and 1
  gload_lds16(gA, &As[0][tid * 8]);
  gload_lds16(gB, &Bs[0][tid * 8]);
  gload_lds16(gA + 32, &As[1][tid * 8]);
  gload_lds16(gB + 32, &Bs[1][tid * 8]);
  asm volatile("s_waitcnt vmcnt(2)" ::: "memory");  // step-0 loads done
  __builtin_amdgcn_s_barrier();
#pragma unroll
  for (int t = 0; t < NSTEP; ++t) {
    const int cur = t % 3;
    if (t + 2 < NSTEP) {
      const int nb = (t + 2) % 3;
      int k0 = (t + 2) << 5;
      gload_lds16(gA + k0, &As[nb][tid * 8]);
      gload_lds16(gB + k0, &Bs[nb][tid * 8]);
    }
    bf16x8 a0 = *(bf16x8*)&As[cur][(wm + fr) * 32 + kg];
    bf16x8 a1 = *(bf16x8*)&As[cur][(wm + 16 + fr) * 32 + kg];
    bf16x8 b0 = *(bf16x8*)&Bs[cur][(wn + fr) * 32 + kg];
    bf16x8 b1 = *(bf16x8*)&Bs[cur][(wn + 16 + fr) * 32 + kg];
    acc[0][0] = __builtin_amdgcn_mfma_f32_16x16x32_bf16(a0, b0, acc[0][0], 0, 0, 0);
    acc[0][1] = __builtin_amdgcn_mfma_f32_16x16x32_bf16(a0, b1, acc[0][1], 0, 0, 0);
    acc[1][0] = __builtin_amdgcn_mfma_f32_16x16x32_bf16(a1, b0, acc[1][0], 0, 0, 0);
    acc[1][1] = __builtin_amdgcn_mfma_f32_16x16x32_bf16(a1, b1, acc[1][1], 0, 0, 0);
    if (t + 2 < NSTEP) {
      // t+1's 2 loads complete; t+2's 2 stay in flight. lgkmcnt(0) makes this
      // wave's ds_reads complete before others may overwrite buf (t+3 reuse).
      asm volatile("s_waitcnt vmcnt(2) lgkmcnt(0)" ::: "memory");
    } else if (t + 1 < NSTEP) {
      asm volatile("s_waitcnt vmcnt(0) lgkmcnt(0)" ::: "memory");
    }
    if (t + 1 < NSTEP) __builtin_amdgcn_s_barrier();
  }
  int rbase = (lane >> 4) << 2;
#pragma unroll
  for (int mi = 0; mi < 2; ++mi)
#pragma unroll
    for (int nj = 0; nj < 2; ++nj)
#pragma unroll
      for (int reg = 0; reg < 4; ++reg) {
        int row = m0 + wm + (mi << 4) + rbase + reg;
        int col = n0 + wn + (nj << 4) + fr;
        float v = acc[mi][nj][reg];
        if (BIAS_MODE == 1) v += bias[row];
        if (BIAS_MODE == 2) v += bias[col];
        if (RESID) v += R[(long)row * N + col];
        Cc[(long)row * N + col] = (OUT_T)v;
      }
}

// ------------------------------------------------------------- attention
// Swapped-operand flash attention, 8 waves/block (128 q-rows), NS-way k-split.
// LDS tiles [64][64] with 16B-chunk rotation (conflict-free, verified r6).
template <int NS>
__global__ __launch_bounds__(512) void attn_k(const bf16* __restrict__ yT,
                                              const bf16* __restrict__ V,
                                              bf16* __restrict__ Op,
                                              float* __restrict__ Mp,
                                              float* __restrict__ Lp) {
  const int n = HW_;
  constexpr int NT = (HW_ / NS) / 64;
  int bh = blockIdx.y, b = bh >> 3, h = bh & 7;
  int split = blockIdx.z;
  int q0 = blockIdx.x * 128;
  int kbeg = split * (n / NS);
  int tid = threadIdx.x, lane = tid & 63, wave = tid >> 6;
  int fr = lane & 15, g = lane >> 4, kg = g << 3;
  const bf16* yTb = yT + (long)b * n * 1024;
  const bf16* Vb = V + ((long)b * C_ + h * 64) * n;
  const bf16* Kb = yTb + 512 + h * 64;

  int qrow = q0 + (wave << 4) + fr;
  const bf16* qp = yTb + (long)qrow * 1024 + h * 64;
  bf16x8 qf0 = *(const bf16x8*)(qp + kg);
  bf16x8 qf1 = *(const bf16x8*)(qp + 32 + kg);

  __shared__ __align__(16) bf16 Kt[2][64][64];  // [buf][k][rot(d)]
  __shared__ __align__(16) bf16 Vt[2][64][64];  // [buf][d][rot(slot(k))]

  int o0 = ((g + fr) & 7) << 3;
  int o1 = ((4 + g + fr) & 7) << 3;

  float m_run = -1e30f, l_run = 0.f;
  f32x4 oacc[4] = {};

  int r0 = tid >> 3;
  int ck = tid & 7;
  int c0e = ck << 3;
  int pk = ((ck + r0) & 7) << 3;
  int vs = (c0e & 32) | ((c0e & 8) << 1) | ((c0e & 16) >> 2);
  int cv = vs >> 3, sub = vs & 7;
  int pv0 = (((cv + r0) & 7) << 3) + sub;
  int pv1 = (((cv + 1 + r0) & 7) << 3) + sub;

  const bf16* kptr = Kb + (long)(kbeg + r0) * 1024 + c0e;
  const bf16* vptr = Vb + (long)r0 * n + kbeg + c0e;
  uint4 rk = *(const uint4*)kptr;
  uint4 rv = *(const uint4*)vptr;
  *(uint4*)&Kt[0][r0][pk] = rk;
  *(uint2*)&Vt[0][r0][pv0] = make_uint2(rv.x, rv.y);
  *(uint2*)&Vt[0][r0][pv1] = make_uint2(rv.z, rv.w);
  kptr += 64 * 1024;
  vptr += 64;
  rk = *(const uint4*)kptr;
  rv = *(const uint4*)vptr;
  __syncthreads();

  for (int t = 0; t < NT; ++t) {
    int cur = t & 1;
    // S^T = K @ Q^T
    f32x4 s[4] = {};
    __builtin_amdgcn_s_setprio(1);
#pragma unroll
    for (int nj = 0; nj < 4; ++nj) {
      bf16x8 kf0 = *(bf16x8*)&Kt[cur][(nj << 4) + fr][o0];
      bf16x8 kf1 = *(bf16x8*)&Kt[cur][(nj << 4) + fr][o1];
      s[nj] = __builtin_amdgcn_mfma_f32_16x16x32_bf16(kf0, qf0, s[nj], 0, 0, 0);
      s[nj] = __builtin_amdgcn_mfma_f32_16x16x32_bf16(kf1, qf1, s[nj], 0, 0, 0);
    }
    __builtin_amdgcn_s_setprio(0);
    if (t + 1 < NT) {
      int nb = cur ^ 1;
      *(uint4*)&Kt[nb][r0][pk] = rk;
      *(uint2*)&Vt[nb][r0][pv0] = make_uint2(rv.x, rv.y);
      *(uint2*)&Vt[nb][r0][pv1] = make_uint2(rv.z, rv.w);
      if (t + 2 < NT) {
        kptr += 64 * 1024;
        vptr += 64;
        rk = *(const uint4*)kptr;
        rv = *(const uint4*)vptr;
      }
    }
    // online softmax (lane-local rows)
    float pm = fmaxf(fmaxf(s[0][0], s[0][1]), fmaxf(s[0][2], s[0][3]));
#pragma unroll
    for (int nj = 1; nj < 4; ++nj)
      pm = fmaxf(pm, fmaxf(fmaxf(s[nj][0], s[nj][1]), fmaxf(s[nj][2], s[nj][3])));
    pm = fmaxf(pm, __shfl_xor(pm, 16));
    pm = fmaxf(pm, __shfl_xor(pm, 32));
    if (__any(pm > m_run + THR_)) {
      float mn = fmaxf(m_run, pm);
      float corr = EXP2(m_run - mn);
      m_run = mn;
      l_run *= corr;
#pragma unroll
      for (int dj = 0; dj < 4; ++dj)
#pragma unroll
        for (int r = 0; r < 4; ++r) oacc[dj][r] *= corr;
    }
    float ls = 0.f;
    bf16x8 pa0, pa1;
#pragma unroll
    for (int r = 0; r < 4; ++r) {
      float p0 = EXP2(s[0][r] - m_run);
      float p1 = EXP2(s[1][r] - m_run);
      float p2 = EXP2(s[2][r] - m_run);
      float p3 = EXP2(s[3][r] - m_run);
      ls += (p0 + p1) + (p2 + p3);
      pa0[r] = (bf16)p0;
      pa0[4 + r] = (bf16)p1;
      pa1[r] = (bf16)p2;
      pa1[4 + r] = (bf16)p3;
    }
    ls += __shfl_xor(ls, 16);
    ls += __shfl_xor(ls, 32);
    l_run += ls;
    // O^T += V^T @ P
    __builtin_amdgcn_s_setprio(1);
#pragma unroll
    for (int dj = 0; dj < 4; ++dj) {
      bf16x8 vf0 = *(bf16x8*)&Vt[cur][(dj << 4) + fr][o0];
      bf16x8 vf1 = *(bf16x8*)&Vt[cur][(dj << 4) + fr][o1];
      oacc[dj] = __builtin_amdgcn_mfma_f32_16x16x32_bf16(vf0, pa0, oacc[dj], 0, 0, 0);
      oacc[dj] = __builtin_amdgcn_mfma_f32_16x16x32_bf16(vf1, pa1, oacc[dj], 0, 0, 0);
    }
    __builtin_amdgcn_s_setprio(0);
    __syncthreads();
  }
  long orow = (long)(split * 16 + bh) * n + q0 + (wave << 4) + fr;
#pragma unroll
  for (int dj = 0; dj < 4; ++dj) {
    bf16x4 ov = {(bf16)oacc[dj][0], (bf16)oacc[dj][1], (bf16)oacc[dj][2], (bf16)oacc[dj][3]};
    *(bf16x4*)&Op[orow * 64 + (dj << 4) + (g << 2)] = ov;
  }
  if (g == 0) {
    Mp[orow] = m_run;
    Lp[orow] = l_run;
  }
}

// ----------------------------------------------------------- split merge
template <int NS>
__global__ __launch_bounds__(256) void attn_merge_k(const bf16* __restrict__ Op,
                                                    const float* __restrict__ Mp,
                                                    const float* __restrict__ Lp,
                                                    bf16* __restrict__ aT) {
  int bh = blockIdx.y, b = bh >> 3, h = bh & 7;
  int gi = blockIdx.x * 256 + threadIdx.x;
  int nrow = gi >> 3, dd8 = (gi & 7) << 3;
  long idx[NS];
  float mm = -1e30f;
#pragma unroll
  for (int s = 0; s < NS; ++s) {
    idx[s] = (long)(s * 16 + bh) * HW_ + nrow;
    mm = fmaxf(mm, Mp[idx[s]]);
  }
  float l = 0.f, w[NS];
#pragma unroll
  for (int s = 0; s < NS; ++s) {
    w[s] = EXP2(Mp[idx[s]] - mm);
    l += Lp[idx[s]] * w[s];
  }
  float invl = 1.f / l;
  float oaccf[8] = {};
#pragma unroll
  for (int s = 0; s < NS; ++s) {
    bf16x8 o = *(const bf16x8*)&Op[idx[s] * 64 + dd8];
    float ws = w[s] * invl;
#pragma unroll
    for (int j = 0; j < 8; ++j) oaccf[j] += (float)o[j] * ws;
  }
  bf16x8 o;
#pragma unroll
  for (int j = 0; j < 8; ++j) o[j] = (bf16)oaccf[j];
  *(bf16x8*)&aT[((long)b * HW_ + nrow) * C_ + h * 64 + dd8] = o;
}

// ----------------------------------------------------------------- launch
extern "C" void kernel_launch(void* const* d_in, const int* in_sizes, int n_in,
                              void* d_out, int out_size, void* d_ws, size_t ws_size,
                              hipStream_t stream) {
  const float* x = (const float*)d_in[0];
  const float* gn_w = (const float*)d_in[1];
  const float* gn_b = (const float*)d_in[2];
  const float* qkv_w = (const float*)d_in[3];
  const float* qkv_b = (const float*)d_in[4];
  const float* proj_w = (const float*)d_in[5];
  const float* proj_b = (const float*)d_in[6];
  float* out = (float*)d_out;

  char* ws = (char*)d_ws;
  float* ps = (float*)ws;   ws += 2048;
  float* pss = (float*)ws;  ws += 2048;
  float* bqk = (float*)ws;  ws += 4096;
  float* bv = (float*)ws;   ws += 2048;
  bf16* wqk = (bf16*)ws;    ws += 1024l * 512 * 2;
  bf16* wv = (bf16*)ws;     ws += 512l * 512 * 2;
  bf16* wp = (bf16*)ws;     ws += 512l * 512 * 2;
  bf16* xnT = (bf16*)ws;    ws += 2l * HW_ * 512 * 2;
  bf16* yT = (bf16*)ws;     ws += 2l * HW_ * 1024 * 2;
  bf16* v = (bf16*)ws;      ws += 2l * 512 * HW_ * 2;
  bf16* aT = (bf16*)ws;     ws += 2l * HW_ * 512 * 2;
  bf16* Op = (bf16*)ws;     // NS*16*HW*64 bf16
  size_t base_used = (size_t)(ws - (char*)d_ws);
  size_t need4 = base_used + 4ull * 16 * HW_ * 64 * 2 + 2ull * 4 * 16 * HW_ * 4;
  int NS = (ws_size >= need4) ? 4 : 2;
  ws += (size_t)NS * 16 * HW_ * 64 * 2;
  float* Mp = (float*)ws;   ws += (size_t)NS * 16 * HW_ * 4;
  float* Lp = (float*)ws;   ws += (size_t)NS * 16 * HW_ * 4;

  gn_stats_part_k<<<512, 256, 0, stream>>>(x, ps, pss);
  prep_w_k<<<2048, 256, 0, stream>>>(qkv_w, qkv_b, proj_w, wqk, wv, wp, bqk, bv);
  gn_apply_k<<<dim3(36, 16, 2), 256, 0, stream>>>(x, gn_w, gn_b, ps, pss, xnT);
  // yT[b][n][r] = xnT @ wqk^T + bqk   (M=2304, N=1024, K=512)
  gemm_k<2, false, bf16><<<dim3(16, 36, 2), 256, 0, stream>>>(
      xnT, wqk, bqk, nullptr, yT, 2304, 1024, (long)HW_ * 512, 0, (long)HW_ * 1024);
  // v[b][hd][n] = wv @ xnT^T + bv     (M=512, N=2304, K=512)
  gemm_k<1, false, bf16><<<dim3(36, 8, 2), 256, 0, stream>>>(
      wv, xnT, bv, nullptr, v, 512, 2304, 0, (long)HW_ * 512, 512l * HW_);
  if (NS == 4) {
    attn_k<4><<<dim3(18, 16, 4), 512, 0, stream>>>(yT, v, Op, Mp, Lp);
    attn_merge_k<4><<<dim3(72, 16), 256, 0, stream>>>(Op, Mp, Lp, aT);
  } else {
    attn_k<2><<<dim3(18, 16, 2), 512, 0, stream>>>(yT, v, Op, Mp, Lp);
    attn_merge_k<2><<<dim3(72, 16), 256, 0, stream>>>(Op, Mp, Lp, aT);
  }
  // out = wp @ aT^T + proj_b + x      (M=512, N=2304, K=512), fp32 out
  gemm_k<1, true, float><<<dim3(36, 8, 2), 256, 0, stream>>>(
      wp, aT, proj_b, x, out, 512, 2304, 0, (long)HW_ * 512, 512l * HW_);
}

// Round 9
// 85.683 us; speedup vs baseline: 1.9505x; 1.0963x over previous
//
#include <hip/hip_runtime.h>

typedef __bf16 bf16;
typedef __bf16 bf16x8 __attribute__((ext_vector_type(8)));
typedef __bf16 bf16x4 __attribute__((ext_vector_type(4)));
typedef float f32x4 __attribute__((ext_vector_type(4)));

#define B_ 2
#define C_ 512
#define HW_ 2304
#define GROUPS_ 32
#define CPG_ 16
#define EPS_ 1e-5f
#define THR_ 8.0f            // log2 units
#define LOG2E_ 1.44269504f
#define EXP2(x) __builtin_amdgcn_exp2f(x)

// async global->LDS, 16B per lane; LDS dest linear in lane order.
__device__ __forceinline__ void gload_lds16(const bf16* g, bf16* l) {
  __builtin_amdgcn_global_load_lds((const __attribute__((address_space(1))) void*)g,
                                   (__attribute__((address_space(3))) void*)l, 16, 0, 0);
}

// -------------------------------- fused: gn partial stats + weight prep
// blocks [0,512): stats (bg = blk>>3, seg = blk&7). blocks [512,2560): prep.
__global__ __launch_bounds__(256) void pre_k(const float* __restrict__ x,
                                             const float* __restrict__ qkv_w,
                                             const float* __restrict__ qkv_b,
                                             const float* __restrict__ proj_w,
                                             float* __restrict__ ps,
                                             float* __restrict__ pss,
                                             bf16* __restrict__ wqk,
                                             bf16* __restrict__ wv,
                                             bf16* __restrict__ wp,
                                             float* __restrict__ bqk,
                                             float* __restrict__ bv) {
  int blk = blockIdx.x;
  if (blk < 512) {
    int bg = blk >> 3, seg = blk & 7;
    const int n4 = CPG_ * HW_ / 4 / 8;  // 1152
    const float4* p = (const float4*)(x + (long)bg * CPG_ * HW_) + (long)seg * n4;
    float s = 0.f, ss = 0.f;
    for (int i = threadIdx.x; i < n4; i += 256) {
      float4 v = p[i];
      s += v.x + v.y + v.z + v.w;
      ss += v.x * v.x + v.y * v.y + v.z * v.z + v.w * v.w;
    }
#pragma unroll
    for (int d = 1; d < 64; d <<= 1) { s += __shfl_xor(s, d); ss += __shfl_xor(ss, d); }
    __shared__ float rs[4], rss[4];
    int wave = threadIdx.x >> 6, lane = threadIdx.x & 63;
    if (lane == 0) { rs[wave] = s; rss[wave] = ss; }
    __syncthreads();
    if (threadIdx.x == 0) {
      ps[blk] = rs[0] + rs[1] + rs[2] + rs[3];
      pss[blk] = rss[0] + rss[1] + rss[2] + rss[3];
    }
  } else {
    int idx = (blk - 512) * 256 + threadIdx.x;
    int r = idx >> 9, c = idx & 511;
    {
      int src = (r < 512) ? 3 * r : 3 * (r - 512) + 1;
      float sc = (r < 512) ? 0.125f * LOG2E_ : 1.0f;
      wqk[idx] = (bf16)(qkv_w[(long)src * 512 + c] * sc);
    }
    if (r < 512) {
      wv[idx] = (bf16)(qkv_w[(long)(3 * r + 2) * 512 + c]);
      wp[idx] = (bf16)(proj_w[idx]);
    }
    if (idx < 1024) {
      int src = (idx < 512) ? 3 * idx : 3 * (idx - 512) + 1;
      float sc = (idx < 512) ? 0.125f * LOG2E_ : 1.0f;
      bqk[idx] = qkv_b[src] * sc;
    }
    if (idx < 512) bv[idx] = qkv_b[3 * idx + 2];
  }
}

// ------------------- gn apply + transpose->bf16 (finalizes stats inline)
__global__ __launch_bounds__(256) void gn_apply_k(const float* __restrict__ x,
                                                  const float* __restrict__ gw,
                                                  const float* __restrict__ gb,
                                                  const float* __restrict__ ps,
                                                  const float* __restrict__ pss,
                                                  bf16* __restrict__ xnT) {
  int n0 = blockIdx.x * 64, c0 = blockIdx.y * 32, b = blockIdx.z;
  int nn = n0 + (threadIdx.x & 63);
  int cb = c0 + ((threadIdx.x >> 6) << 3);
  int gi = b * GROUPS_ + (cb >> 4);
  float s = 0.f, ss = 0.f;
#pragma unroll
  for (int k = 0; k < 8; ++k) { s += ps[gi * 8 + k]; ss += pss[gi * 8 + k]; }
  const float invN = 1.0f / (float)(CPG_ * HW_);
  float mu = s * invN;
  float var = ss * invN - mu * mu;
  float rstd = rsqrtf(var + EPS_);
  bf16x8 o;
#pragma unroll
  for (int j = 0; j < 8; ++j) {
    int c = cb + j;
    float sc = rstd * gw[c];
    float sh = gb[c] - mu * sc;
    float v = x[((long)b * C_ + c) * HW_ + nn];
    o[j] = (bf16)(v * sc + sh);
  }
  *(bf16x8*)&xnT[((long)b * HW_ + nn) * C_ + cb] = o;
}

// ------------------------------------------------------------ GEMM 64x64
// C[M][N] = A(MxK rm) * BT(NxK rm)^T, K=512. 4 waves (2x2 of 32x32), BK=64,
// 3-buffer gload_lds pipeline, prefetch distance 2, counted vmcnt(4).
// LDS rows are 128B -> 16B-chunk rotation swizzle: global source pre-rotated
// by row ((ck+row)&7), reads inverse-rotated ((chunk-row)&7). Conflict-free.
template <int BIAS_MODE, bool RESID, typename OUT_T>
__global__ __launch_bounds__(256) void gemm_k(const bf16* __restrict__ A,
                                              const bf16* __restrict__ BT,
                                              const float* __restrict__ bias,
                                              const float* __restrict__ resid,
                                              OUT_T* __restrict__ Cc,
                                              int M, int N,
                                              long sA, long sBT, long sC) {
  constexpr int KK = 512;
  constexpr int NSTEP = KK >> 6;  // 8
  int b = blockIdx.z;
  A += sA * b;
  BT += sBT * b;
  Cc += sC * b;
  const float* R = RESID ? (resid + sC * b) : nullptr;
  int m0 = blockIdx.y * 64, n0 = blockIdx.x * 64;
  int tid = threadIdx.x, lane = tid & 63, wave = tid >> 6;
  int wm = (wave >> 1) << 5, wn = (wave & 1) << 5;
  int fr = lane & 15, g = lane >> 4;
  __shared__ __align__(16) bf16 As[3][64 * 64];
  __shared__ __align__(16) bf16 Bs[3][64 * 64];
  int sr = tid >> 3;                          // staging row 0..31 (and +32)
  int swz = (((tid & 7) + sr) & 7) << 3;      // rotated source chunk
  const bf16* gA = A + (long)(m0 + sr) * KK + swz;
  const bf16* gB = BT + (long)(n0 + sr) * KK + swz;
  // read offsets: logical chunk c at row fr lives in slot (c - fr) & 7
  int o0 = ((g - fr) & 7) << 3;        // chunk g     (k 0..31 slice)
  int o1 = ((4 + g - fr) & 7) << 3;    // chunk 4+g   (k 32..63 slice)
  f32x4 acc[2][2] = {};
  // prologue: stage steps 0,1
  gload_lds16(gA, &As[0][tid * 8]);
  gload_lds16(gA + 32 * KK, &As[0][2048 + tid * 8]);
  gload_lds16(gB, &Bs[0][tid * 8]);
  gload_lds16(gB + 32 * KK, &Bs[0][2048 + tid * 8]);
  gload_lds16(gA + 64, &As[1][tid * 8]);
  gload_lds16(gA + 32 * KK + 64, &As[1][2048 + tid * 8]);
  gload_lds16(gB + 64, &Bs[1][tid * 8]);
  gload_lds16(gB + 32 * KK + 64, &Bs[1][2048 + tid * 8]);
  asm volatile("s_waitcnt vmcnt(4)" ::: "memory");  // step-0 loads done
  __builtin_amdgcn_s_barrier();
#pragma unroll
  for (int t = 0; t < NSTEP; ++t) {
    const int cur = t % 3;
    if (t + 2 < NSTEP) {
      const int nb = (t + 2) % 3;
      int k0 = (t + 2) << 6;
      gload_lds16(gA + k0, &As[nb][tid * 8]);
      gload_lds16(gA + 32 * KK + k0, &As[nb][2048 + tid * 8]);
      gload_lds16(gB + k0, &Bs[nb][tid * 8]);
      gload_lds16(gB + 32 * KK + k0, &Bs[nb][2048 + tid * 8]);
    }
    bf16x8 a00 = *(bf16x8*)&As[cur][(wm + fr) * 64 + o0];
    bf16x8 a01 = *(bf16x8*)&As[cur][(wm + fr) * 64 + o1];
    bf16x8 a10 = *(bf16x8*)&As[cur][(wm + 16 + fr) * 64 + o0];
    bf16x8 a11 = *(bf16x8*)&As[cur][(wm + 16 + fr) * 64 + o1];
    bf16x8 b00 = *(bf16x8*)&Bs[cur][(wn + fr) * 64 + o0];
    bf16x8 b01 = *(bf16x8*)&Bs[cur][(wn + fr) * 64 + o1];
    bf16x8 b10 = *(bf16x8*)&Bs[cur][(wn + 16 + fr) * 64 + o0];
    bf16x8 b11 = *(bf16x8*)&Bs[cur][(wn + 16 + fr) * 64 + o1];
    acc[0][0] = __builtin_amdgcn_mfma_f32_16x16x32_bf16(a00, b00, acc[0][0], 0, 0, 0);
    acc[0][0] = __builtin_amdgcn_mfma_f32_16x16x32_bf16(a01, b01, acc[0][0], 0, 0, 0);
    acc[0][1] = __builtin_amdgcn_mfma_f32_16x16x32_bf16(a00, b10, acc[0][1], 0, 0, 0);
    acc[0][1] = __builtin_amdgcn_mfma_f32_16x16x32_bf16(a01, b11, acc[0][1], 0, 0, 0);
    acc[1][0] = __builtin_amdgcn_mfma_f32_16x16x32_bf16(a10, b00, acc[1][0], 0, 0, 0);
    acc[1][0] = __builtin_amdgcn_mfma_f32_16x16x32_bf16(a11, b01, acc[1][0], 0, 0, 0);
    acc[1][1] = __builtin_amdgcn_mfma_f32_16x16x32_bf16(a10, b10, acc[1][1], 0, 0, 0);
    acc[1][1] = __builtin_amdgcn_mfma_f32_16x16x32_bf16(a11, b11, acc[1][1], 0, 0, 0);
    if (t + 2 < NSTEP) {
      // t+1's 4 loads complete; t+2's 4 stay in flight. lgkmcnt(0): this
      // wave's ds_reads done before barrier (buf reused by t+1's prefetch).
      asm volatile("s_waitcnt vmcnt(4) lgkmcnt(0)" ::: "memory");
    } else if (t + 1 < NSTEP) {
      asm volatile("s_waitcnt vmcnt(0) lgkmcnt(0)" ::: "memory");
    }
    if (t + 1 < NSTEP) __builtin_amdgcn_s_barrier();
  }
  int rbase = (lane >> 4) << 2;
#pragma unroll
  for (int mi = 0; mi < 2; ++mi)
#pragma unroll
    for (int nj = 0; nj < 2; ++nj)
#pragma unroll
      for (int reg = 0; reg < 4; ++reg) {
        int row = m0 + wm + (mi << 4) + rbase + reg;
        int col = n0 + wn + (nj << 4) + fr;
        float v = acc[mi][nj][reg];
        if (BIAS_MODE == 1) v += bias[row];
        if (BIAS_MODE == 2) v += bias[col];
        if (RESID) v += R[(long)row * N + col];
        Cc[(long)row * N + col] = (OUT_T)v;
      }
}

// ------------------------------------------------------------- attention
// Swapped-operand flash attention, 8 waves/block (128 q-rows), NS-way k-split.
// LDS tiles [64][64] with 16B-chunk rotation (conflict-free, verified r6).
template <int NS>
__global__ __launch_bounds__(512) void attn_k(const bf16* __restrict__ yT,
                                              const bf16* __restrict__ V,
                                              bf16* __restrict__ Op,
                                              float* __restrict__ Mp,
                                              float* __restrict__ Lp) {
  const int n = HW_;
  constexpr int NT = (HW_ / NS) / 64;
  int bh = blockIdx.y, b = bh >> 3, h = bh & 7;
  int split = blockIdx.z;
  int q0 = blockIdx.x * 128;
  int kbeg = split * (n / NS);
  int tid = threadIdx.x, lane = tid & 63, wave = tid >> 6;
  int fr = lane & 15, g = lane >> 4, kg = g << 3;
  const bf16* yTb = yT + (long)b * n * 1024;
  const bf16* Vb = V + ((long)b * C_ + h * 64) * n;
  const bf16* Kb = yTb + 512 + h * 64;

  int qrow = q0 + (wave << 4) + fr;
  const bf16* qp = yTb + (long)qrow * 1024 + h * 64;
  bf16x8 qf0 = *(const bf16x8*)(qp + kg);
  bf16x8 qf1 = *(const bf16x8*)(qp + 32 + kg);

  __shared__ __align__(16) bf16 Kt[2][64][64];  // [buf][k][rot(d)]
  __shared__ __align__(16) bf16 Vt[2][64][64];  // [buf][d][rot(slot(k))]

  int o0 = ((g + fr) & 7) << 3;
  int o1 = ((4 + g + fr) & 7) << 3;

  float m_run = -1e30f, l_run = 0.f;
  f32x4 oacc[4] = {};

  int r0 = tid >> 3;
  int ck = tid & 7;
  int c0e = ck << 3;
  int pk = ((ck + r0) & 7) << 3;
  int vs = (c0e & 32) | ((c0e & 8) << 1) | ((c0e & 16) >> 2);
  int cv = vs >> 3, sub = vs & 7;
  int pv0 = (((cv + r0) & 7) << 3) + sub;
  int pv1 = (((cv + 1 + r0) & 7) << 3) + sub;

  const bf16* kptr = Kb + (long)(kbeg + r0) * 1024 + c0e;
  const bf16* vptr = Vb + (long)r0 * n + kbeg + c0e;
  uint4 rk = *(const uint4*)kptr;
  uint4 rv = *(const uint4*)vptr;
  *(uint4*)&Kt[0][r0][pk] = rk;
  *(uint2*)&Vt[0][r0][pv0] = make_uint2(rv.x, rv.y);
  *(uint2*)&Vt[0][r0][pv1] = make_uint2(rv.z, rv.w);
  kptr += 64 * 1024;
  vptr += 64;
  rk = *(const uint4*)kptr;
  rv = *(const uint4*)vptr;
  __syncthreads();

  for (int t = 0; t < NT; ++t) {
    int cur = t & 1;
    // S^T = K @ Q^T
    f32x4 s[4] = {};
    __builtin_amdgcn_s_setprio(1);
#pragma unroll
    for (int nj = 0; nj < 4; ++nj) {
      bf16x8 kf0 = *(bf16x8*)&Kt[cur][(nj << 4) + fr][o0];
      bf16x8 kf1 = *(bf16x8*)&Kt[cur][(nj << 4) + fr][o1];
      s[nj] = __builtin_amdgcn_mfma_f32_16x16x32_bf16(kf0, qf0, s[nj], 0, 0, 0);
      s[nj] = __builtin_amdgcn_mfma_f32_16x16x32_bf16(kf1, qf1, s[nj], 0, 0, 0);
    }
    __builtin_amdgcn_s_setprio(0);
    if (t + 1 < NT) {
      int nb = cur ^ 1;
      *(uint4*)&Kt[nb][r0][pk] = rk;
      *(uint2*)&Vt[nb][r0][pv0] = make_uint2(rv.x, rv.y);
      *(uint2*)&Vt[nb][r0][pv1] = make_uint2(rv.z, rv.w);
      if (t + 2 < NT) {
        kptr += 64 * 1024;
        vptr += 64;
        rk = *(const uint4*)kptr;
        rv = *(const uint4*)vptr;
      }
    }
    // online softmax (lane-local rows)
    float pm = fmaxf(fmaxf(s[0][0], s[0][1]), fmaxf(s[0][2], s[0][3]));
#pragma unroll
    for (int nj = 1; nj < 4; ++nj)
      pm = fmaxf(pm, fmaxf(fmaxf(s[nj][0], s[nj][1]), fmaxf(s[nj][2], s[nj][3])));
    pm = fmaxf(pm, __shfl_xor(pm, 16));
    pm = fmaxf(pm, __shfl_xor(pm, 32));
    if (__any(pm > m_run + THR_)) {
      float mn = fmaxf(m_run, pm);
      float corr = EXP2(m_run - mn);
      m_run = mn;
      l_run *= corr;
#pragma unroll
      for (int dj = 0; dj < 4; ++dj)
#pragma unroll
        for (int r = 0; r < 4; ++r) oacc[dj][r] *= corr;
    }
    float ls = 0.f;
    bf16x8 pa0, pa1;
#pragma unroll
    for (int r = 0; r < 4; ++r) {
      float p0 = EXP2(s[0][r] - m_run);
      float p1 = EXP2(s[1][r] - m_run);
      float p2 = EXP2(s[2][r] - m_run);
      float p3 = EXP2(s[3][r] - m_run);
      ls += (p0 + p1) + (p2 + p3);
      pa0[r] = (bf16)p0;
      pa0[4 + r] = (bf16)p1;
      pa1[r] = (bf16)p2;
      pa1[4 + r] = (bf16)p3;
    }
    ls += __shfl_xor(ls, 16);
    ls += __shfl_xor(ls, 32);
    l_run += ls;
    // O^T += V^T @ P
    __builtin_amdgcn_s_setprio(1);
#pragma unroll
    for (int dj = 0; dj < 4; ++dj) {
      bf16x8 vf0 = *(bf16x8*)&Vt[cur][(dj << 4) + fr][o0];
      bf16x8 vf1 = *(bf16x8*)&Vt[cur][(dj << 4) + fr][o1];
      oacc[dj] = __builtin_amdgcn_mfma_f32_16x16x32_bf16(vf0, pa0, oacc[dj], 0, 0, 0);
      oacc[dj] = __builtin_amdgcn_mfma_f32_16x16x32_bf16(vf1, pa1, oacc[dj], 0, 0, 0);
    }
    __builtin_amdgcn_s_setprio(0);
    __syncthreads();
  }
  long orow = (long)(split * 16 + bh) * n + q0 + (wave << 4) + fr;
#pragma unroll
  for (int dj = 0; dj < 4; ++dj) {
    bf16x4 ov = {(bf16)oacc[dj][0], (bf16)oacc[dj][1], (bf16)oacc[dj][2], (bf16)oacc[dj][3]};
    *(bf16x4*)&Op[orow * 64 + (dj << 4) + (g << 2)] = ov;
  }
  if (g == 0) {
    Mp[orow] = m_run;
    Lp[orow] = l_run;
  }
}

// ----------------------------------------------------------- split merge
template <int NS>
__global__ __launch_bounds__(256) void attn_merge_k(const bf16* __restrict__ Op,
                                                    const float* __restrict__ Mp,
                                                    const float* __restrict__ Lp,
                                                    bf16* __restrict__ aT) {
  int bh = blockIdx.y, b = bh >> 3, h = bh & 7;
  int gi = blockIdx.x * 256 + threadIdx.x;
  int nrow = gi >> 3, dd8 = (gi & 7) << 3;
  long idx[NS];
  float mm = -1e30f;
#pragma unroll
  for (int s = 0; s < NS; ++s) {
    idx[s] = (long)(s * 16 + bh) * HW_ + nrow;
    mm = fmaxf(mm, Mp[idx[s]]);
  }
  float l = 0.f, w[NS];
#pragma unroll
  for (int s = 0; s < NS; ++s) {
    w[s] = EXP2(Mp[idx[s]] - mm);
    l += Lp[idx[s]] * w[s];
  }
  float invl = 1.f / l;
  float oaccf[8] = {};
#pragma unroll
  for (int s = 0; s < NS; ++s) {
    bf16x8 o = *(const bf16x8*)&Op[idx[s] * 64 + dd8];
    float ws = w[s] * invl;
#pragma unroll
    for (int j = 0; j < 8; ++j) oaccf[j] += (float)o[j] * ws;
  }
  bf16x8 o;
#pragma unroll
  for (int j = 0; j < 8; ++j) o[j] = (bf16)oaccf[j];
  *(bf16x8*)&aT[((long)b * HW_ + nrow) * C_ + h * 64 + dd8] = o;
}

// ----------------------------------------------------------------- launch
extern "C" void kernel_launch(void* const* d_in, const int* in_sizes, int n_in,
                              void* d_out, int out_size, void* d_ws, size_t ws_size,
                              hipStream_t stream) {
  const float* x = (const float*)d_in[0];
  const float* gn_w = (const float*)d_in[1];
  const float* gn_b = (const float*)d_in[2];
  const float* qkv_w = (const float*)d_in[3];
  const float* qkv_b = (const float*)d_in[4];
  const float* proj_w = (const float*)d_in[5];
  const float* proj_b = (const float*)d_in[6];
  float* out = (float*)d_out;

  char* ws = (char*)d_ws;
  float* ps = (float*)ws;   ws += 2048;
  float* pss = (float*)ws;  ws += 2048;
  float* bqk = (float*)ws;  ws += 4096;
  float* bv = (float*)ws;   ws += 2048;
  bf16* wqk = (bf16*)ws;    ws += 1024l * 512 * 2;
  bf16* wv = (bf16*)ws;     ws += 512l * 512 * 2;
  bf16* wp = (bf16*)ws;     ws += 512l * 512 * 2;
  bf16* xnT = (bf16*)ws;    ws += 2l * HW_ * 512 * 2;
  bf16* yT = (bf16*)ws;     ws += 2l * HW_ * 1024 * 2;
  bf16* v = (bf16*)ws;      ws += 2l * 512 * HW_ * 2;
  bf16* aT = (bf16*)ws;     ws += 2l * HW_ * 512 * 2;
  bf16* Op = (bf16*)ws;     // NS*16*HW*64 bf16
  size_t base_used = (size_t)(ws - (char*)d_ws);
  size_t need4 = base_used + 4ull * 16 * HW_ * 64 * 2 + 2ull * 4 * 16 * HW_ * 4;
  int NS = (ws_size >= need4) ? 4 : 2;
  ws += (size_t)NS * 16 * HW_ * 64 * 2;
  float* Mp = (float*)ws;   ws += (size_t)NS * 16 * HW_ * 4;
  float* Lp = (float*)ws;   ws += (size_t)NS * 16 * HW_ * 4;

  pre_k<<<2560, 256, 0, stream>>>(x, qkv_w, qkv_b, proj_w, ps, pss, wqk, wv, wp, bqk, bv);
  gn_apply_k<<<dim3(36, 16, 2), 256, 0, stream>>>(x, gn_w, gn_b, ps, pss, xnT);
  // yT[b][n][r] = xnT @ wqk^T + bqk   (M=2304, N=1024, K=512)
  gemm_k<2, false, bf16><<<dim3(16, 36, 2), 256, 0, stream>>>(
      xnT, wqk, bqk, nullptr, yT, 2304, 1024, (long)HW_ * 512, 0, (long)HW_ * 1024);
  // v[b][hd][n] = wv @ xnT^T + bv     (M=512, N=2304, K=512)
  gemm_k<1, false, bf16><<<dim3(36, 8, 2), 256, 0, stream>>>(
      wv, xnT, bv, nullptr, v, 512, 2304, 0, (long)HW_ * 512, 512l * HW_);
  if (NS == 4) {
    attn_k<4><<<dim3(18, 16, 4), 512, 0, stream>>>(yT, v, Op, Mp, Lp);
    attn_merge_k<4><<<dim3(72, 16), 256, 0, stream>>>(Op, Mp, Lp, aT);
  } else {
    attn_k<2><<<dim3(18, 16, 2), 512, 0, stream>>>(yT, v, Op, Mp, Lp);
    attn_merge_k<2><<<dim3(72, 16), 256, 0, stream>>>(Op, Mp, Lp, aT);
  }
  // out = wp @ aT^T + proj_b + x      (M=512, N=2304, K=512), fp32 out
  gemm_k<1, true, float><<<dim3(36, 8, 2), 256, 0, stream>>>(
      wp, aT, proj_b, x, out, 512, 2304, 0, (long)HW_ * 512, 512l * HW_);
}